// Round 4
// baseline (624.545 us; speedup 1.0000x reference)
//
#include <hip/hip_runtime.h>

#define E_TOTAL 800000
#define N_TOTAL 50000
#define NBINS   50176   // 196*256, padded

typedef __attribute__((ext_vector_type(8))) short short8;
typedef __attribute__((ext_vector_type(4))) float floatx4;

__device__ __forceinline__ unsigned short f2bf(float f) {
    union { float f; unsigned u; } x; x.f = f;
    unsigned r = x.u + 0x7fff + ((x.u >> 16) & 1);   // RNE
    return (unsigned short)(r >> 16);
}

// ---------------- fused prep: weight transpose + mi zero + h->bf16 + hist zero ----------------
__global__ __launch_bounds__(256)
void prep(const float* __restrict__ We1, const float* __restrict__ We2,
          const float* __restrict__ Wh1, const float* __restrict__ Wh2,
          unsigned short* __restrict__ W1t, unsigned short* __restrict__ W2t,
          unsigned short* __restrict__ Wh1t, unsigned short* __restrict__ Wh2t,
          const float* __restrict__ h, unsigned short* __restrict__ hbf,
          int do_cvt, int do_sort,
          float* __restrict__ mi, int* __restrict__ hist)
{
    const int b = blockIdx.x;
    const int tid = threadIdx.x;
    if (b < 400) {
        int t = b * 256 + tid;
        if (t < 36864) {
            W1t[(t & 127) * 288 + (t >> 7)] = f2bf(We1[t]);
        } else if (t < 53248) {
            t -= 36864;
            W2t[(t & 127) * 128 + (t >> 7)] = f2bf(We2[t]);
        } else if (t < 86016) {
            t -= 53248;
            Wh1t[(t & 127) * 256 + (t >> 7)] = f2bf(Wh1[t]);
        } else if (t < 102400) {
            t -= 86016;
            Wh2t[(t & 127) * 128 + (t >> 7)] = f2bf(Wh2[t]);
        }
    } else if (b < 6650) {
        const int t = (b - 400) * 256 + tid;
        ((float4*)mi)[t] = make_float4(0.f, 0.f, 0.f, 0.f);
    } else if (b < 9775) {
        if (do_cvt) {
            const int t = (b - 6650) * 256 + tid;
            const float4* h4 = (const float4*)h;
            float4 a = h4[(size_t)t * 2];
            float4 c = h4[(size_t)t * 2 + 1];
            short8 v = { (short)f2bf(a.x), (short)f2bf(a.y), (short)f2bf(a.z), (short)f2bf(a.w),
                         (short)f2bf(c.x), (short)f2bf(c.y), (short)f2bf(c.z), (short)f2bf(c.w) };
            *(short8*)(&hbf[(size_t)t * 8]) = v;
        }
    } else {
        if (do_sort) hist[(b - 9775) * 256 + tid] = 0;
    }
}

// ---------------- counting sort of edge ids by dst ----------------
__global__ __launch_bounds__(256) void k_hist(const int* __restrict__ ei, int* __restrict__ hist) {
    const int t = blockIdx.x * 256 + threadIdx.x;
    atomicAdd(&hist[ei[E_TOTAL + t]], 1);
}
__global__ __launch_bounds__(256) void k_scan1(const int* __restrict__ hist, int* __restrict__ partial) {
    __shared__ int s[256];
    s[threadIdx.x] = hist[blockIdx.x * 256 + threadIdx.x];
    __syncthreads();
    for (int off = 128; off > 0; off >>= 1) {
        if (threadIdx.x < off) s[threadIdx.x] += s[threadIdx.x + off];
        __syncthreads();
    }
    if (threadIdx.x == 0) partial[blockIdx.x] = s[0];
}
__global__ __launch_bounds__(256)
void k_scan2(const int* __restrict__ partial, int* __restrict__ partialOff) {
    __shared__ int s[256];
    const int t = threadIdx.x;
    const int NP = NBINS / 256;   // 196
    const int v = (t < NP) ? partial[t] : 0;
    s[t] = v; __syncthreads();
    for (int off = 1; off < 256; off <<= 1) {
        int x = (t >= off) ? s[t - off] : 0;
        __syncthreads();
        s[t] += x;
        __syncthreads();
    }
    if (t < NP) partialOff[t] = s[t] - v;   // exclusive prefix
}
__global__ __launch_bounds__(256)
void k_scan3(const int* __restrict__ hist, const int* __restrict__ partialOff,
             int* __restrict__ cursor) {
    __shared__ int s[256];
    const int t = threadIdx.x, g = blockIdx.x * 256 + t;
    const int v = hist[g];
    s[t] = v; __syncthreads();
    for (int off = 1; off < 256; off <<= 1) {
        int x = (t >= off) ? s[t - off] : 0;
        __syncthreads();
        s[t] += x;
        __syncthreads();
    }
    cursor[g] = partialOff[blockIdx.x] + s[t] - v;   // exclusive prefix
}
// scatter: emit sorted src/dst ids AND sorted bf16 edge attrs so the edge
// kernel has zero indirection (no perm, no ei, linear ea reads).
__global__ __launch_bounds__(256)
void k_scatter(const int* __restrict__ ei, const float* __restrict__ ea,
               int* __restrict__ cursor,
               int* __restrict__ srcS, int* __restrict__ dstS,
               unsigned short* __restrict__ eabf) {
    const int t = blockIdx.x * 256 + threadIdx.x;
    const int src = ei[t];
    const int dst = ei[E_TOTAL + t];
    const int pos = atomicAdd(&cursor[dst], 1);
    srcS[pos] = src;
    dstS[pos] = dst;
    const float4* ea4 = (const float4*)ea;
    #pragma unroll
    for (int j = 0; j < 4; ++j) {
        float4 a = ea4[(size_t)t * 8 + j * 2];
        float4 b = ea4[(size_t)t * 8 + j * 2 + 1];
        short8 v = { (short)f2bf(a.x), (short)f2bf(a.y), (short)f2bf(a.z), (short)f2bf(a.w),
                     (short)f2bf(b.x), (short)f2bf(b.y), (short)f2bf(b.z), (short)f2bf(b.w) };
        *(short8*)(&eabf[(size_t)pos * 32 + j * 8]) = v;
    }
}

// ================= MFMA kernels =================
constexpr int XK = 296;  // 288 + 8 pad
constexpr int HK = 136;  // 128 + 8 pad
constexpr int NK = 264;  // 256 + 8 pad
constexpr int FJ = 132;  // fp32 epilogue tile stride

// ---- persistent pipelined sorted edge kernel ----
// 1024 blocks x 256 thr (4 waves), exactly 4 blocks/CU resident; each block
// grid-strides over ~12 tiles of 64 sorted edges. Staging for tile t+1 is
// issued into REGISTERS right after tile t's LDS-write barrier, so global
// latency hides under tile t's GEMM1+GEMM2+epilogue (T14/T3 pattern).
// Staging has no dependent chains: srcS/dstS broadcast reads + linear eabf.
__global__ __launch_bounds__(256, 4)
void edge_mfma_sorted(const unsigned short* __restrict__ hbf,
                      const int* __restrict__ srcS,
                      const int* __restrict__ dstS,
                      const unsigned short* __restrict__ eabf,
                      const unsigned short* __restrict__ W1t,  // [128][288]
                      const float* __restrict__ b1,
                      const unsigned short* __restrict__ W2t,  // [128][128]
                      const float* __restrict__ b2,
                      float* __restrict__ mi)
{
    constexpr int NT = E_TOTAL / 64;   // 12500 tiles
    __shared__ alignas(16) unsigned short sMem[64 * XK];  // aliased: sX / sH / sF
    __shared__ int sDstA[64];

    const int tid  = threadIdx.x;
    const short8* hbf8 = (const short8*)hbf;
    const short8* eab8 = (const short8*)eabf;

    const int lane = tid & 63;
    const int w    = tid >> 6;     // 0..3: column group
    const int q    = lane >> 4;
    const int lr   = lane & 15;
    const int n0   = w * 32;

    // staged next-tile registers
    short8 rh[8];
    short8 rea;
    int    rdst = 0;

    // per-thread invariants for the h staging loop: c fixed per thread
    const int sc  = tid & 31;        // chunk 0..31
    const int se0 = tid >> 5;        // base edge within tile (stride 8 per item)
    const int scc = sc & 15;         // chunk within node row

    auto LOADR = [&](int tile) {
        const int e0 = tile * 64;
        const int* nodeArr = (sc < 16) ? srcS : dstS;
        #pragma unroll
        for (int k = 0; k < 8; ++k) {
            const int node = nodeArr[e0 + se0 + k * 8];
            rh[k] = hbf8[(size_t)node * 16 + scc];
        }
        rea = eab8[(size_t)tile * 256 + tid];
        if (tid < 64) rdst = dstS[e0 + tid];
    };

    int tile = blockIdx.x;
    LOADR(tile);

    while (tile < NT) {
        // ---- write staged tile -> LDS ----
        {
            const int base = se0 * XK + sc * 8;
            #pragma unroll
            for (int k = 0; k < 8; ++k)
                *(short8*)(&sMem[base + k * 8 * XK]) = rh[k];
            const int e = tid >> 2, c = tid & 3;
            *(short8*)(&sMem[e * XK + 256 + c * 8]) = rea;
            if (tid < 64) sDstA[tid] = rdst;
        }
        __syncthreads();

        const int nxt = tile + (int)gridDim.x;
        if (nxt < NT) LOADR(nxt);     // issue next-tile loads; latency hides below

        // ---- GEMM1: 64x288 @ 288x32 ----
        floatx4 acc[4][2];
        #pragma unroll
        for (int mt = 0; mt < 4; ++mt)
            #pragma unroll
            for (int nt = 0; nt < 2; ++nt)
                acc[mt][nt] = (floatx4){0.f, 0.f, 0.f, 0.f};

        #pragma unroll
        for (int ks = 0; ks < 9; ++ks) {
            const int kb = ks * 32 + q * 8;
            short8 a[4], b[2];
            #pragma unroll
            for (int nt = 0; nt < 2; ++nt)
                b[nt] = *(const short8*)(&W1t[(n0 + nt * 16 + lr) * 288 + kb]);
            #pragma unroll
            for (int mt = 0; mt < 4; ++mt)
                a[mt] = *(const short8*)(&sMem[(mt * 16 + lr) * XK + kb]);
            #pragma unroll
            for (int mt = 0; mt < 4; ++mt)
                #pragma unroll
                for (int nt = 0; nt < 2; ++nt)
                    acc[mt][nt] = __builtin_amdgcn_mfma_f32_16x16x32_bf16(
                        a[mt], b[nt], acc[mt][nt], 0, 0, 0);
        }
        __syncthreads();

        {
            float bias[2] = { b1[n0 + lr], b1[n0 + 16 + lr] };
            #pragma unroll
            for (int mt = 0; mt < 4; ++mt)
                #pragma unroll
                for (int nt = 0; nt < 2; ++nt)
                    #pragma unroll
                    for (int r = 0; r < 4; ++r) {
                        float v = fmaxf(acc[mt][nt][r] + bias[nt], 0.f);
                        sMem[(mt * 16 + q * 4 + r) * HK + n0 + nt * 16 + lr] = f2bf(v);
                    }
        }
        __syncthreads();

        // ---- GEMM2: 64x128 @ 128x32 ----
        floatx4 acc2[4][2];
        #pragma unroll
        for (int mt = 0; mt < 4; ++mt)
            #pragma unroll
            for (int nt = 0; nt < 2; ++nt)
                acc2[mt][nt] = (floatx4){0.f, 0.f, 0.f, 0.f};

        #pragma unroll
        for (int ks = 0; ks < 4; ++ks) {
            const int kb = ks * 32 + q * 8;
            short8 a[4], b[2];
            #pragma unroll
            for (int nt = 0; nt < 2; ++nt)
                b[nt] = *(const short8*)(&W2t[(n0 + nt * 16 + lr) * 128 + kb]);
            #pragma unroll
            for (int mt = 0; mt < 4; ++mt)
                a[mt] = *(const short8*)(&sMem[(mt * 16 + lr) * HK + kb]);
            #pragma unroll
            for (int mt = 0; mt < 4; ++mt)
                #pragma unroll
                for (int nt = 0; nt < 2; ++nt)
                    acc2[mt][nt] = __builtin_amdgcn_mfma_f32_16x16x32_bf16(
                        a[mt], b[nt], acc2[mt][nt], 0, 0, 0);
        }
        __syncthreads();   // GEMM2 LDS reads done before fp32 tile overwrite

        // ---- m_ij tile -> LDS (fp32) ----
        float* sF = (float*)sMem;   // [64][FJ]
        {
            float bias[2] = { b2[n0 + lr], b2[n0 + 16 + lr] };
            #pragma unroll
            for (int mt = 0; mt < 4; ++mt)
                #pragma unroll
                for (int nt = 0; nt < 2; ++nt)
                    #pragma unroll
                    for (int r = 0; r < 4; ++r)
                        sF[(mt * 16 + q * 4 + r) * FJ + n0 + nt * 16 + lr] =
                            acc2[mt][nt][r] + bias[nt];
        }
        __syncthreads();

        // ---- run-length-reduced scatter ----
        {
            const int g  = tid >> 7;        // 0..1
            const int j  = tid & 127;
            const int r0 = g * 32;
            float sum = 0.f;
            for (int r = r0; r < r0 + 32; ++r) {
                sum += sF[r * FJ + j];
                const int dst = sDstA[r];
                if (r == r0 + 31 || sDstA[r + 1] != dst) {   // wave-uniform branch
                    atomicAdd(&mi[(size_t)dst * 128 + j], sum);
                    sum = 0.f;
                }
            }
        }
        __syncthreads();   // sF reads done before next tile's LDS write

        tile = nxt;
    }
}

// ---- flat fallback edge kernel ----
template <bool PRECVT>
__global__ __launch_bounds__(256, 8)
void edge_mfma_flat(const float* __restrict__ h,
                    const unsigned short* __restrict__ hbf,
                    const int* __restrict__ ei,
                    const float* __restrict__ ea,
                    const unsigned short* __restrict__ W1t,
                    const float* __restrict__ b1,
                    const unsigned short* __restrict__ W2t,
                    const float* __restrict__ b2,
                    float* __restrict__ mi)
{
    __shared__ unsigned short sMem[32 * XK];
    __shared__ int sDst[32];

    const int tid = threadIdx.x;
    const int e0  = blockIdx.x * 32;
    if (tid < 32) sDst[tid] = ei[E_TOTAL + e0 + tid];

    const float4* h4   = (const float4*)h;
    const short8* hbf8 = (const short8*)hbf;
    const float4* ea4  = (const float4*)ea;
    #pragma unroll
    for (int it = 0; it < 5; ++it) {
        const int idx = tid + it * 256;
        const int e  = idx / 40;
        const int c  = idx - e * 40;
        const int ge = e0 + e;
        if (c < 32) {
            const int node = (c < 16) ? ei[ge] : ei[E_TOTAL + ge];
            const int cc = c & 15;
            short8 v;
            if (PRECVT) {
                v = hbf8[(size_t)node * 16 + cc];
            } else {
                float4 x = h4[(size_t)node * 32 + cc * 2];
                float4 y = h4[(size_t)node * 32 + cc * 2 + 1];
                v = (short8){ (short)f2bf(x.x), (short)f2bf(x.y), (short)f2bf(x.z), (short)f2bf(x.w),
                              (short)f2bf(y.x), (short)f2bf(y.y), (short)f2bf(y.z), (short)f2bf(y.w) };
            }
            *(short8*)(&sMem[e * XK + c * 8]) = v;
        } else {
            float4 x = ea4[(size_t)ge * 8 + (c - 32)];
            unsigned short* p = &sMem[e * XK + 128 + c * 4];
            p[0] = f2bf(x.x); p[1] = f2bf(x.y); p[2] = f2bf(x.z); p[3] = f2bf(x.w);
        }
    }
    __syncthreads();

    const int lane = tid & 63;
    const int w    = tid >> 6;
    const int q    = lane >> 4;
    const int lr   = lane & 15;
    const int n0   = w * 32;

    floatx4 acc[2][2];
    #pragma unroll
    for (int mt = 0; mt < 2; ++mt)
        #pragma unroll
        for (int nt = 0; nt < 2; ++nt)
            acc[mt][nt] = (floatx4){0.f, 0.f, 0.f, 0.f};
    #pragma unroll
    for (int ks = 0; ks < 9; ++ks) {
        const int kb = ks * 32 + q * 8;
        short8 a[2], b[2];
        #pragma unroll
        for (int mt = 0; mt < 2; ++mt)
            a[mt] = *(const short8*)(&sMem[(mt * 16 + lr) * XK + kb]);
        #pragma unroll
        for (int nt = 0; nt < 2; ++nt)
            b[nt] = *(const short8*)(&W1t[(n0 + nt * 16 + lr) * 288 + kb]);
        #pragma unroll
        for (int mt = 0; mt < 2; ++mt)
            #pragma unroll
            for (int nt = 0; nt < 2; ++nt)
                acc[mt][nt] = __builtin_amdgcn_mfma_f32_16x16x32_bf16(
                    a[mt], b[nt], acc[mt][nt], 0, 0, 0);
    }
    __syncthreads();
    {
        float bias[2] = { b1[n0 + lr], b1[n0 + 16 + lr] };
        #pragma unroll
        for (int mt = 0; mt < 2; ++mt)
            #pragma unroll
            for (int nt = 0; nt < 2; ++nt)
                #pragma unroll
                for (int r = 0; r < 4; ++r) {
                    float v = fmaxf(acc[mt][nt][r] + bias[nt], 0.f);
                    sMem[(mt * 16 + q * 4 + r) * HK + n0 + nt * 16 + lr] = f2bf(v);
                }
    }
    __syncthreads();
    floatx4 acc2[2][2];
    #pragma unroll
    for (int mt = 0; mt < 2; ++mt)
        #pragma unroll
        for (int nt = 0; nt < 2; ++nt)
            acc2[mt][nt] = (floatx4){0.f, 0.f, 0.f, 0.f};
    #pragma unroll
    for (int ks = 0; ks < 4; ++ks) {
        const int kb = ks * 32 + q * 8;
        short8 a[2], b[2];
        #pragma unroll
        for (int mt = 0; mt < 2; ++mt)
            a[mt] = *(const short8*)(&sMem[(mt * 16 + lr) * HK + kb]);
        #pragma unroll
        for (int nt = 0; nt < 2; ++nt)
            b[nt] = *(const short8*)(&W2t[(n0 + nt * 16 + lr) * 128 + kb]);
        #pragma unroll
        for (int mt = 0; mt < 2; ++mt)
            #pragma unroll
            for (int nt = 0; nt < 2; ++nt)
                acc2[mt][nt] = __builtin_amdgcn_mfma_f32_16x16x32_bf16(
                    a[mt], b[nt], acc2[mt][nt], 0, 0, 0);
    }
    {
        float bias[2] = { b2[n0 + lr], b2[n0 + 16 + lr] };
        #pragma unroll
        for (int mt = 0; mt < 2; ++mt)
            #pragma unroll
            for (int r = 0; r < 4; ++r) {
                const int m   = mt * 16 + q * 4 + r;
                const int dst = sDst[m];
                float* row = &mi[(size_t)dst * 128];
                #pragma unroll
                for (int nt = 0; nt < 2; ++nt)
                    atomicAdd(&row[n0 + nt * 16 + lr], acc2[mt][nt][r] + bias[nt]);
            }
    }
}

// ---- node kernel: stages h from pre-converted hbf when available ----
template <bool USEHBF>
__global__ __launch_bounds__(256, 8)
void node_mfma(const float* __restrict__ h,
               const unsigned short* __restrict__ hbf,
               const float* __restrict__ mi,
               const unsigned short* __restrict__ W1t,
               const float* __restrict__ b1,
               const unsigned short* __restrict__ W2t,
               const float* __restrict__ b2,
               float* __restrict__ out)
{
    __shared__ unsigned short sMem[32 * NK];

    const int tid = threadIdx.x;
    const int g0  = blockIdx.x * 32;

    const float4* h4   = (const float4*)h;
    const short8* hbf8 = (const short8*)hbf;
    const float4* mi4  = (const float4*)mi;
    if (USEHBF) {
        #pragma unroll
        for (int it = 0; it < 2; ++it) {
            const int idx = tid + it * 256;
            const int n  = idx >> 4;
            const int c  = idx & 15;
            const int gn = g0 + n;
            short8 v = (short8){0,0,0,0,0,0,0,0};
            if (gn < N_TOTAL) v = hbf8[(size_t)gn * 16 + c];
            *(short8*)(&sMem[n * NK + c * 8]) = v;
        }
        #pragma unroll
        for (int it = 0; it < 4; ++it) {
            const int idx = tid + it * 256;
            const int n  = idx >> 5;
            const int c  = idx & 31;
            const int gn = g0 + n;
            float4 v = make_float4(0.f, 0.f, 0.f, 0.f);
            if (gn < N_TOTAL) v = mi4[(size_t)gn * 32 + c];
            unsigned short* p = &sMem[n * NK + 128 + c * 4];
            p[0] = f2bf(v.x); p[1] = f2bf(v.y); p[2] = f2bf(v.z); p[3] = f2bf(v.w);
        }
    } else {
        #pragma unroll
        for (int it = 0; it < 8; ++it) {
            const int idx = tid + it * 256;
            const int n  = idx >> 6;
            const int c  = idx & 63;
            const int gn = g0 + n;
            float4 v = make_float4(0.f, 0.f, 0.f, 0.f);
            if (gn < N_TOTAL)
                v = (c < 32) ? h4[(size_t)gn * 32 + c] : mi4[(size_t)gn * 32 + (c - 32)];
            unsigned short* p = &sMem[n * NK + c * 4];
            p[0] = f2bf(v.x); p[1] = f2bf(v.y); p[2] = f2bf(v.z); p[3] = f2bf(v.w);
        }
    }
    __syncthreads();

    const int lane = tid & 63;
    const int w    = tid >> 6;
    const int q    = lane >> 4;
    const int lr   = lane & 15;
    const int n0   = w * 32;

    floatx4 acc[2][2];
    #pragma unroll
    for (int mt = 0; mt < 2; ++mt)
        #pragma unroll
        for (int nt = 0; nt < 2; ++nt)
            acc[mt][nt] = (floatx4){0.f, 0.f, 0.f, 0.f};
    #pragma unroll
    for (int ks = 0; ks < 8; ++ks) {
        const int kb = ks * 32 + q * 8;
        short8 a[2], b[2];
        #pragma unroll
        for (int mt = 0; mt < 2; ++mt)
            a[mt] = *(const short8*)(&sMem[(mt * 16 + lr) * NK + kb]);
        #pragma unroll
        for (int nt = 0; nt < 2; ++nt)
            b[nt] = *(const short8*)(&W1t[(n0 + nt * 16 + lr) * 256 + kb]);
        #pragma unroll
        for (int mt = 0; mt < 2; ++mt)
            #pragma unroll
            for (int nt = 0; nt < 2; ++nt)
                acc[mt][nt] = __builtin_amdgcn_mfma_f32_16x16x32_bf16(
                    a[mt], b[nt], acc[mt][nt], 0, 0, 0);
    }
    __syncthreads();
    {
        float bias[2] = { b1[n0 + lr], b1[n0 + 16 + lr] };
        #pragma unroll
        for (int mt = 0; mt < 2; ++mt)
            #pragma unroll
            for (int nt = 0; nt < 2; ++nt)
                #pragma unroll
                for (int r = 0; r < 4; ++r) {
                    float v = fmaxf(acc[mt][nt][r] + bias[nt], 0.f);
                    sMem[(mt * 16 + q * 4 + r) * HK + n0 + nt * 16 + lr] = f2bf(v);
                }
    }
    __syncthreads();
    floatx4 acc2[2][2];
    #pragma unroll
    for (int mt = 0; mt < 2; ++mt)
        #pragma unroll
        for (int nt = 0; nt < 2; ++nt)
            acc2[mt][nt] = (floatx4){0.f, 0.f, 0.f, 0.f};
    #pragma unroll
    for (int ks = 0; ks < 4; ++ks) {
        const int kb = ks * 32 + q * 8;
        short8 a[2], b[2];
        #pragma unroll
        for (int mt = 0; mt < 2; ++mt)
            a[mt] = *(const short8*)(&sMem[(mt * 16 + lr) * HK + kb]);
        #pragma unroll
        for (int nt = 0; nt < 2; ++nt)
            b[nt] = *(const short8*)(&W2t[(n0 + nt * 16 + lr) * 128 + kb]);
        #pragma unroll
        for (int mt = 0; mt < 2; ++mt)
            #pragma unroll
            for (int nt = 0; nt < 2; ++nt)
                acc2[mt][nt] = __builtin_amdgcn_mfma_f32_16x16x32_bf16(
                    a[mt], b[nt], acc2[mt][nt], 0, 0, 0);
    }
    {
        float bias[2] = { b2[n0 + lr], b2[n0 + 16 + lr] };
        #pragma unroll
        for (int mt = 0; mt < 2; ++mt)
            #pragma unroll
            for (int r = 0; r < 4; ++r) {
                const int gm = g0 + mt * 16 + q * 4 + r;
                if (gm < N_TOTAL) {
                    #pragma unroll
                    for (int nt = 0; nt < 2; ++nt)
                        out[(size_t)gm * 128 + n0 + nt * 16 + lr] =
                            acc2[mt][nt][r] + bias[nt];
                }
            }
    }
}

extern "C" void kernel_launch(void* const* d_in, const int* in_sizes, int n_in,
                              void* d_out, int out_size, void* d_ws, size_t ws_size,
                              hipStream_t stream) {
    const float* h   = (const float*)d_in[0];
    const int*   ei  = (const int*)d_in[1];
    const float* ea  = (const float*)d_in[2];
    const float* We1 = (const float*)d_in[3];
    const float* be1 = (const float*)d_in[4];
    const float* We2 = (const float*)d_in[5];
    const float* be2 = (const float*)d_in[6];
    const float* Wh1 = (const float*)d_in[7];
    const float* bh1 = (const float*)d_in[8];
    const float* Wh2 = (const float*)d_in[9];
    const float* bh2 = (const float*)d_in[10];
    float* out = (float*)d_out;

    const size_t szMi   = (size_t)N_TOTAL * 128 * sizeof(float);
    const size_t szW1t  = 128 * 288 * 2;
    const size_t szW2t  = 128 * 128 * 2;
    const size_t szWh1t = 128 * 256 * 2;
    const size_t szWh2t = 128 * 128 * 2;
    const size_t szHbf  = (size_t)N_TOTAL * 128 * 2;
    const size_t szIds  = (size_t)E_TOTAL * 4;           // srcS / dstS each
    const size_t szEabf = (size_t)E_TOTAL * 32 * 2;      // sorted bf16 edge attrs
    const size_t szHist = (size_t)NBINS * 4;

    const size_t offW1t  = szMi;
    const size_t offW2t  = offW1t + szW1t;
    const size_t offWh1t = offW2t + szW2t;
    const size_t offWh2t = offWh1t + szWh1t;
    const size_t offHbf  = offWh2t + szWh2t;
    const size_t offSrc  = offHbf + szHbf;
    const size_t offDst  = offSrc + szIds;
    const size_t offEabf = offDst + szIds;
    const size_t offHist = offEabf + szEabf;
    const size_t offCur  = offHist + szHist;
    const size_t offP1   = offCur + szHist;
    const size_t offP2   = offP1 + 1024;
    const size_t needFull = offP2 + 1024;
    const size_t needCvt  = offSrc;

    char* wsb = (char*)d_ws;
    float* mi = (float*)wsb;
    unsigned short* W1t  = (unsigned short*)(wsb + offW1t);
    unsigned short* W2t  = (unsigned short*)(wsb + offW2t);
    unsigned short* Wh1t = (unsigned short*)(wsb + offWh1t);
    unsigned short* Wh2t = (unsigned short*)(wsb + offWh2t);
    unsigned short* hbf  = (unsigned short*)(wsb + offHbf);
    int* srcS    = (int*)(wsb + offSrc);
    int* dstS    = (int*)(wsb + offDst);
    unsigned short* eabf = (unsigned short*)(wsb + offEabf);
    int* hist    = (int*)(wsb + offHist);
    int* cursor  = (int*)(wsb + offCur);
    int* partial = (int*)(wsb + offP1);
    int* poff    = (int*)(wsb + offP2);

    const int full   = (ws_size >= needFull) ? 1 : 0;
    const int do_cvt = (ws_size >= needCvt + szHbf) ? 1 : 0;

    prep<<<9971, 256, 0, stream>>>(We1, We2, Wh1, Wh2, W1t, W2t, Wh1t, Wh2t,
                                   h, hbf, do_cvt, full, mi, hist);

    if (full) {
        k_hist<<<E_TOTAL / 256, 256, 0, stream>>>(ei, hist);
        k_scan1<<<NBINS / 256, 256, 0, stream>>>(hist, partial);
        k_scan2<<<1, 256, 0, stream>>>(partial, poff);
        k_scan3<<<NBINS / 256, 256, 0, stream>>>(hist, poff, cursor);
        k_scatter<<<E_TOTAL / 256, 256, 0, stream>>>(ei, ea, cursor, srcS, dstS, eabf);
        edge_mfma_sorted<<<1024, 256, 0, stream>>>(
            hbf, srcS, dstS, eabf, W1t, be1, W2t, be2, mi);
        node_mfma<true><<<(N_TOTAL + 31) / 32, 256, 0, stream>>>(
            h, hbf, mi, Wh1t, bh1, Wh2t, bh2, out);
    } else if (do_cvt) {
        edge_mfma_flat<true><<<E_TOTAL / 32, 256, 0, stream>>>(
            h, hbf, ei, ea, W1t, be1, W2t, be2, mi);
        node_mfma<true><<<(N_TOTAL + 31) / 32, 256, 0, stream>>>(
            h, hbf, mi, Wh1t, bh1, Wh2t, bh2, out);
    } else {
        edge_mfma_flat<false><<<E_TOTAL / 32, 256, 0, stream>>>(
            h, nullptr, ei, ea, W1t, be1, W2t, be2, mi);
        node_mfma<false><<<(N_TOTAL + 31) / 32, 256, 0, stream>>>(
            h, nullptr, mi, Wh1t, bh1, Wh2t, bh2, out);
    }
    (void)in_sizes; (void)n_in; (void)out_size;
}

// Round 5
// 617.508 us; speedup vs baseline: 1.0114x; 1.0114x over previous
//
#include <hip/hip_runtime.h>

#define E_TOTAL 800000
#define N_TOTAL 50000
#define NBINS   50176   // 196*256, padded

typedef __attribute__((ext_vector_type(8))) short short8;
typedef __attribute__((ext_vector_type(4))) float floatx4;

__device__ __forceinline__ unsigned short f2bf(float f) {
    union { float f; unsigned u; } x; x.f = f;
    unsigned r = x.u + 0x7fff + ((x.u >> 16) & 1);   // RNE
    return (unsigned short)(r >> 16);
}

// ---------------- fused prep: weight transpose + mi zero + h->bf16 + hist zero ----------------
__global__ __launch_bounds__(256)
void prep(const float* __restrict__ We1, const float* __restrict__ We2,
          const float* __restrict__ Wh1, const float* __restrict__ Wh2,
          unsigned short* __restrict__ W1t, unsigned short* __restrict__ W2t,
          unsigned short* __restrict__ Wh1t, unsigned short* __restrict__ Wh2t,
          const float* __restrict__ h, unsigned short* __restrict__ hbf,
          int do_cvt, int do_sort,
          float* __restrict__ mi, int* __restrict__ hist)
{
    const int b = blockIdx.x;
    const int tid = threadIdx.x;
    if (b < 400) {
        int t = b * 256 + tid;
        if (t < 36864) {
            W1t[(t & 127) * 288 + (t >> 7)] = f2bf(We1[t]);
        } else if (t < 53248) {
            t -= 36864;
            W2t[(t & 127) * 128 + (t >> 7)] = f2bf(We2[t]);
        } else if (t < 86016) {
            t -= 53248;
            Wh1t[(t & 127) * 256 + (t >> 7)] = f2bf(Wh1[t]);
        } else if (t < 102400) {
            t -= 86016;
            Wh2t[(t & 127) * 128 + (t >> 7)] = f2bf(Wh2[t]);
        }
    } else if (b < 6650) {
        const int t = (b - 400) * 256 + tid;
        ((float4*)mi)[t] = make_float4(0.f, 0.f, 0.f, 0.f);
    } else if (b < 9775) {
        if (do_cvt) {
            const int t = (b - 6650) * 256 + tid;
            const float4* h4 = (const float4*)h;
            float4 a = h4[(size_t)t * 2];
            float4 c = h4[(size_t)t * 2 + 1];
            short8 v = { (short)f2bf(a.x), (short)f2bf(a.y), (short)f2bf(a.z), (short)f2bf(a.w),
                         (short)f2bf(c.x), (short)f2bf(c.y), (short)f2bf(c.z), (short)f2bf(c.w) };
            *(short8*)(&hbf[(size_t)t * 8]) = v;
        }
    } else {
        if (do_sort) hist[(b - 9775) * 256 + tid] = 0;
    }
}

// ---------------- counting sort of edge ids by dst ----------------
__global__ __launch_bounds__(256) void k_hist(const int* __restrict__ ei, int* __restrict__ hist) {
    const int t = blockIdx.x * 256 + threadIdx.x;
    atomicAdd(&hist[ei[E_TOTAL + t]], 1);
}
__global__ __launch_bounds__(256) void k_scan1(const int* __restrict__ hist, int* __restrict__ partial) {
    __shared__ int s[256];
    s[threadIdx.x] = hist[blockIdx.x * 256 + threadIdx.x];
    __syncthreads();
    for (int off = 128; off > 0; off >>= 1) {
        if (threadIdx.x < off) s[threadIdx.x] += s[threadIdx.x + off];
        __syncthreads();
    }
    if (threadIdx.x == 0) partial[blockIdx.x] = s[0];
}
__global__ __launch_bounds__(256)
void k_scan2(const int* __restrict__ partial, int* __restrict__ partialOff) {
    __shared__ int s[256];
    const int t = threadIdx.x;
    const int NP = NBINS / 256;   // 196
    const int v = (t < NP) ? partial[t] : 0;
    s[t] = v; __syncthreads();
    for (int off = 1; off < 256; off <<= 1) {
        int x = (t >= off) ? s[t - off] : 0;
        __syncthreads();
        s[t] += x;
        __syncthreads();
    }
    if (t < NP) partialOff[t] = s[t] - v;   // exclusive prefix
}
__global__ __launch_bounds__(256)
void k_scan3(const int* __restrict__ hist, const int* __restrict__ partialOff,
             int* __restrict__ cursor) {
    __shared__ int s[256];
    const int t = threadIdx.x, g = blockIdx.x * 256 + t;
    const int v = hist[g];
    s[t] = v; __syncthreads();
    for (int off = 1; off < 256; off <<= 1) {
        int x = (t >= off) ? s[t - off] : 0;
        __syncthreads();
        s[t] += x;
        __syncthreads();
    }
    cursor[g] = partialOff[blockIdx.x] + s[t] - v;   // exclusive prefix
}
// scatter: emit sorted src/dst ids AND sorted bf16 edge attrs so the edge
// kernel has zero indirection (no perm, no ei, linear ea reads).
__global__ __launch_bounds__(256)
void k_scatter(const int* __restrict__ ei, const float* __restrict__ ea,
               int* __restrict__ cursor,
               int* __restrict__ srcS, int* __restrict__ dstS,
               unsigned short* __restrict__ eabf) {
    const int t = blockIdx.x * 256 + threadIdx.x;
    const int src = ei[t];
    const int dst = ei[E_TOTAL + t];
    const int pos = atomicAdd(&cursor[dst], 1);
    srcS[pos] = src;
    dstS[pos] = dst;
    const float4* ea4 = (const float4*)ea;
    #pragma unroll
    for (int j = 0; j < 4; ++j) {
        float4 a = ea4[(size_t)t * 8 + j * 2];
        float4 b = ea4[(size_t)t * 8 + j * 2 + 1];
        short8 v = { (short)f2bf(a.x), (short)f2bf(a.y), (short)f2bf(a.z), (short)f2bf(a.w),
                     (short)f2bf(b.x), (short)f2bf(b.y), (short)f2bf(b.z), (short)f2bf(b.w) };
        *(short8*)(&eabf[(size_t)pos * 32 + j * 8]) = v;
    }
}

// ================= MFMA kernels =================
constexpr int XK = 296;  // 288 + 8 pad
constexpr int HK = 136;  // 128 + 8 pad
constexpr int NK = 264;  // 256 + 8 pad
constexpr int FJ = 132;  // fp32 epilogue tile stride

#define MFMA8(A, B, C) { \
    C[0][0] = __builtin_amdgcn_mfma_f32_16x16x32_bf16(A[0], B[0], C[0][0], 0, 0, 0); \
    C[0][1] = __builtin_amdgcn_mfma_f32_16x16x32_bf16(A[0], B[1], C[0][1], 0, 0, 0); \
    C[1][0] = __builtin_amdgcn_mfma_f32_16x16x32_bf16(A[1], B[0], C[1][0], 0, 0, 0); \
    C[1][1] = __builtin_amdgcn_mfma_f32_16x16x32_bf16(A[1], B[1], C[1][1], 0, 0, 0); \
    C[2][0] = __builtin_amdgcn_mfma_f32_16x16x32_bf16(A[2], B[0], C[2][0], 0, 0, 0); \
    C[2][1] = __builtin_amdgcn_mfma_f32_16x16x32_bf16(A[2], B[1], C[2][1], 0, 0, 0); \
    C[3][0] = __builtin_amdgcn_mfma_f32_16x16x32_bf16(A[3], B[0], C[3][0], 0, 0, 0); \
    C[3][1] = __builtin_amdgcn_mfma_f32_16x16x32_bf16(A[3], B[1], C[3][1], 0, 0, 0); }

// ---- persistent pipelined sorted edge kernel (v5: software-pipelined GEMMs) ----
// v4 post-mortem: all pipes idle, time invariant across 3 structures -> the
// serial {W-load -> vmcnt -> MFMA} chain per K-step is the critical path
// (compiler never pipelined it: VGPR_Count 52-64 of a 128 budget). v5 forces
// depth-2 prefetch on W fragments and depth-1 on A fragments with explicit
// register rotation (all selections compile-time after unroll).
__global__ __launch_bounds__(256, 4)
void edge_mfma_sorted(const unsigned short* __restrict__ hbf,
                      const int* __restrict__ srcS,
                      const int* __restrict__ dstS,
                      const unsigned short* __restrict__ eabf,
                      const unsigned short* __restrict__ W1t,  // [128][288]
                      const float* __restrict__ b1,
                      const unsigned short* __restrict__ W2t,  // [128][128]
                      const float* __restrict__ b2,
                      float* __restrict__ mi)
{
    constexpr int NT = E_TOTAL / 64;   // 12500 tiles
    __shared__ alignas(16) unsigned short sMem[64 * XK];  // aliased: sX / sH / sF
    __shared__ int sDstA[64];

    const int tid  = threadIdx.x;
    const short8* hbf8 = (const short8*)hbf;
    const short8* eab8 = (const short8*)eabf;

    const int lane = tid & 63;
    const int w    = tid >> 6;     // 0..3: column group
    const int q    = lane >> 4;
    const int lr   = lane & 15;
    const int n0   = w * 32;
    const int q8   = q * 8;

    // per-tile-invariant addresses
    const int a0 = lr * XK, a1 = (16 + lr) * XK, a2 = (32 + lr) * XK, a3 = (48 + lr) * XK;
    const int h0 = lr * HK, h1 = (16 + lr) * HK, h2 = (32 + lr) * HK, h3 = (48 + lr) * HK;
    const int w1b0 = (n0 + lr) * 288, w1b1 = (n0 + 16 + lr) * 288;
    const int w2b0 = (n0 + lr) * 128, w2b1 = (n0 + 16 + lr) * 128;

    const float bias1[2] = { b1[n0 + lr], b1[n0 + 16 + lr] };
    const float bias2[2] = { b2[n0 + lr], b2[n0 + 16 + lr] };

#define LB1(KS, B) { B[0] = *(const short8*)(&W1t[w1b0 + (KS) * 32 + q8]); \
                     B[1] = *(const short8*)(&W1t[w1b1 + (KS) * 32 + q8]); }
#define LA1(KS, A) { A[0] = *(const short8*)(&sMem[a0 + (KS) * 32 + q8]); \
                     A[1] = *(const short8*)(&sMem[a1 + (KS) * 32 + q8]); \
                     A[2] = *(const short8*)(&sMem[a2 + (KS) * 32 + q8]); \
                     A[3] = *(const short8*)(&sMem[a3 + (KS) * 32 + q8]); }
#define LB2(KS, B) { B[0] = *(const short8*)(&W2t[w2b0 + (KS) * 32 + q8]); \
                     B[1] = *(const short8*)(&W2t[w2b1 + (KS) * 32 + q8]); }
#define LA2(KS, A) { A[0] = *(const short8*)(&sMem[h0 + (KS) * 32 + q8]); \
                     A[1] = *(const short8*)(&sMem[h1 + (KS) * 32 + q8]); \
                     A[2] = *(const short8*)(&sMem[h2 + (KS) * 32 + q8]); \
                     A[3] = *(const short8*)(&sMem[h3 + (KS) * 32 + q8]); }

    // staged next-tile registers
    short8 rh[8];
    short8 rea;
    int    rdst = 0;

    // per-thread invariants for the h staging loop
    const int sc  = tid & 31;        // chunk 0..31
    const int se0 = tid >> 5;        // base edge within tile (stride 8 per item)
    const int scc = sc & 15;         // chunk within node row

    auto LOADR = [&](int tile) {
        const int e0 = tile * 64;
        const int* nodeArr = (sc < 16) ? srcS : dstS;
        #pragma unroll
        for (int k = 0; k < 8; ++k) {
            const int node = nodeArr[e0 + se0 + k * 8];
            rh[k] = hbf8[(size_t)node * 16 + scc];
        }
        rea = eab8[(size_t)tile * 256 + tid];
        if (tid < 64) rdst = dstS[e0 + tid];
    };

    int tile = blockIdx.x;
    LOADR(tile);

    while (tile < NT) {
        // ---- write staged tile -> LDS ----
        {
            const int base = se0 * XK + sc * 8;
            #pragma unroll
            for (int k = 0; k < 8; ++k)
                *(short8*)(&sMem[base + k * 8 * XK]) = rh[k];
            const int e = tid >> 2, c = tid & 3;
            *(short8*)(&sMem[e * XK + 256 + c * 8]) = rea;
            if (tid < 64) sDstA[tid] = rdst;
        }
        __syncthreads();

        // ---- GEMM1: 64x288 @ 288x32, sw-pipelined (b depth-2, a depth-1) ----
        floatx4 acc[4][2];
        #pragma unroll
        for (int mt = 0; mt < 4; ++mt)
            #pragma unroll
            for (int nt = 0; nt < 2; ++nt)
                acc[mt][nt] = (floatx4){0.f, 0.f, 0.f, 0.f};

        {
            short8 aX[4], aY[4], bX[2], bY[2];
            LB1(0, bX); LB1(1, bY); LA1(0, aX);
            LA1(1, aY); MFMA8(aX, bX, acc); LB1(2, bX);   // ks0
            LA1(2, aX); MFMA8(aY, bY, acc); LB1(3, bY);   // ks1
            LA1(3, aY); MFMA8(aX, bX, acc); LB1(4, bX);   // ks2
            LA1(4, aX); MFMA8(aY, bY, acc); LB1(5, bY);   // ks3
            LA1(5, aY); MFMA8(aX, bX, acc); LB1(6, bX);   // ks4
            LA1(6, aX); MFMA8(aY, bY, acc); LB1(7, bY);   // ks5
            LA1(7, aY); MFMA8(aX, bX, acc); LB1(8, bX);   // ks6
            LA1(8, aX); MFMA8(aY, bY, acc);               // ks7
            MFMA8(aX, bX, acc);                           // ks8
        }

        // issue next-tile gather now: rh not live during GEMM1, hides under GEMM2+
        const int nxt = tile + (int)gridDim.x;
        if (nxt < NT) LOADR(nxt);
        __syncthreads();

        {
            #pragma unroll
            for (int mt = 0; mt < 4; ++mt)
                #pragma unroll
                for (int nt = 0; nt < 2; ++nt)
                    #pragma unroll
                    for (int r = 0; r < 4; ++r) {
                        float v = fmaxf(acc[mt][nt][r] + bias1[nt], 0.f);
                        sMem[(mt * 16 + q * 4 + r) * HK + n0 + nt * 16 + lr] = f2bf(v);
                    }
        }
        __syncthreads();

        // ---- GEMM2: 64x128 @ 128x32, sw-pipelined ----
        floatx4 acc2[4][2];
        #pragma unroll
        for (int mt = 0; mt < 4; ++mt)
            #pragma unroll
            for (int nt = 0; nt < 2; ++nt)
                acc2[mt][nt] = (floatx4){0.f, 0.f, 0.f, 0.f};

        {
            short8 aX[4], aY[4], bX[2], bY[2];
            LB2(0, bX); LB2(1, bY); LA2(0, aX);
            LA2(1, aY); MFMA8(aX, bX, acc2); LB2(2, bX);  // ks0
            LA2(2, aX); MFMA8(aY, bY, acc2); LB2(3, bY);  // ks1
            LA2(3, aY); MFMA8(aX, bX, acc2);              // ks2
            MFMA8(aY, bY, acc2);                          // ks3
        }
        __syncthreads();   // GEMM2 LDS reads done before fp32 tile overwrite

        // ---- m_ij tile -> LDS (fp32) ----
        float* sF = (float*)sMem;   // [64][FJ]
        {
            #pragma unroll
            for (int mt = 0; mt < 4; ++mt)
                #pragma unroll
                for (int nt = 0; nt < 2; ++nt)
                    #pragma unroll
                    for (int r = 0; r < 4; ++r)
                        sF[(mt * 16 + q * 4 + r) * FJ + n0 + nt * 16 + lr] =
                            acc2[mt][nt][r] + bias2[nt];
        }
        __syncthreads();

        // ---- run-length-reduced scatter ----
        {
            const int g  = tid >> 7;        // 0..1
            const int j  = tid & 127;
            const int r0 = g * 32;
            float sum = 0.f;
            for (int r = r0; r < r0 + 32; ++r) {
                sum += sF[r * FJ + j];
                const int dst = sDstA[r];
                if (r == r0 + 31 || sDstA[r + 1] != dst) {   // wave-uniform branch
                    atomicAdd(&mi[(size_t)dst * 128 + j], sum);
                    sum = 0.f;
                }
            }
        }
        __syncthreads();   // sF reads done before next tile's LDS write

        tile = nxt;
    }
#undef LB1
#undef LA1
#undef LB2
#undef LA2
}

// ---- flat fallback edge kernel ----
template <bool PRECVT>
__global__ __launch_bounds__(256, 8)
void edge_mfma_flat(const float* __restrict__ h,
                    const unsigned short* __restrict__ hbf,
                    const int* __restrict__ ei,
                    const float* __restrict__ ea,
                    const unsigned short* __restrict__ W1t,
                    const float* __restrict__ b1,
                    const unsigned short* __restrict__ W2t,
                    const float* __restrict__ b2,
                    float* __restrict__ mi)
{
    __shared__ unsigned short sMem[32 * XK];
    __shared__ int sDst[32];

    const int tid = threadIdx.x;
    const int e0  = blockIdx.x * 32;
    if (tid < 32) sDst[tid] = ei[E_TOTAL + e0 + tid];

    const float4* h4   = (const float4*)h;
    const short8* hbf8 = (const short8*)hbf;
    const float4* ea4  = (const float4*)ea;
    #pragma unroll
    for (int it = 0; it < 5; ++it) {
        const int idx = tid + it * 256;
        const int e  = idx / 40;
        const int c  = idx - e * 40;
        const int ge = e0 + e;
        if (c < 32) {
            const int node = (c < 16) ? ei[ge] : ei[E_TOTAL + ge];
            const int cc = c & 15;
            short8 v;
            if (PRECVT) {
                v = hbf8[(size_t)node * 16 + cc];
            } else {
                float4 x = h4[(size_t)node * 32 + cc * 2];
                float4 y = h4[(size_t)node * 32 + cc * 2 + 1];
                v = (short8){ (short)f2bf(x.x), (short)f2bf(x.y), (short)f2bf(x.z), (short)f2bf(x.w),
                              (short)f2bf(y.x), (short)f2bf(y.y), (short)f2bf(y.z), (short)f2bf(y.w) };
            }
            *(short8*)(&sMem[e * XK + c * 8]) = v;
        } else {
            float4 x = ea4[(size_t)ge * 8 + (c - 32)];
            unsigned short* p = &sMem[e * XK + 128 + c * 4];
            p[0] = f2bf(x.x); p[1] = f2bf(x.y); p[2] = f2bf(x.z); p[3] = f2bf(x.w);
        }
    }
    __syncthreads();

    const int lane = tid & 63;
    const int w    = tid >> 6;
    const int q    = lane >> 4;
    const int lr   = lane & 15;
    const int n0   = w * 32;

    floatx4 acc[2][2];
    #pragma unroll
    for (int mt = 0; mt < 2; ++mt)
        #pragma unroll
        for (int nt = 0; nt < 2; ++nt)
            acc[mt][nt] = (floatx4){0.f, 0.f, 0.f, 0.f};
    #pragma unroll
    for (int ks = 0; ks < 9; ++ks) {
        const int kb = ks * 32 + q * 8;
        short8 a[2], b[2];
        #pragma unroll
        for (int mt = 0; mt < 2; ++mt)
            a[mt] = *(const short8*)(&sMem[(mt * 16 + lr) * XK + kb]);
        #pragma unroll
        for (int nt = 0; nt < 2; ++nt)
            b[nt] = *(const short8*)(&W1t[(n0 + nt * 16 + lr) * 288 + kb]);
        #pragma unroll
        for (int mt = 0; mt < 2; ++mt)
            #pragma unroll
            for (int nt = 0; nt < 2; ++nt)
                acc[mt][nt] = __builtin_amdgcn_mfma_f32_16x16x32_bf16(
                    a[mt], b[nt], acc[mt][nt], 0, 0, 0);
    }
    __syncthreads();
    {
        float bias[2] = { b1[n0 + lr], b1[n0 + 16 + lr] };
        #pragma unroll
        for (int mt = 0; mt < 2; ++mt)
            #pragma unroll
            for (int nt = 0; nt < 2; ++nt)
                #pragma unroll
                for (int r = 0; r < 4; ++r) {
                    float v = fmaxf(acc[mt][nt][r] + bias[nt], 0.f);
                    sMem[(mt * 16 + q * 4 + r) * HK + n0 + nt * 16 + lr] = f2bf(v);
                }
    }
    __syncthreads();
    floatx4 acc2[2][2];
    #pragma unroll
    for (int mt = 0; mt < 2; ++mt)
        #pragma unroll
        for (int nt = 0; nt < 2; ++nt)
            acc2[mt][nt] = (floatx4){0.f, 0.f, 0.f, 0.f};
    #pragma unroll
    for (int ks = 0; ks < 4; ++ks) {
        const int kb = ks * 32 + q * 8;
        short8 a[2], b[2];
        #pragma unroll
        for (int mt = 0; mt < 2; ++mt)
            a[mt] = *(const short8*)(&sMem[(mt * 16 + lr) * HK + kb]);
        #pragma unroll
        for (int nt = 0; nt < 2; ++nt)
            b[nt] = *(const short8*)(&W2t[(n0 + nt * 16 + lr) * 128 + kb]);
        #pragma unroll
        for (int mt = 0; mt < 2; ++mt)
            #pragma unroll
            for (int nt = 0; nt < 2; ++nt)
                acc2[mt][nt] = __builtin_amdgcn_mfma_f32_16x16x32_bf16(
                    a[mt], b[nt], acc2[mt][nt], 0, 0, 0);
    }
    {
        float bias[2] = { b2[n0 + lr], b2[n0 + 16 + lr] };
        #pragma unroll
        for (int mt = 0; mt < 2; ++mt)
            #pragma unroll
            for (int r = 0; r < 4; ++r) {
                const int m   = mt * 16 + q * 4 + r;
                const int dst = sDst[m];
                float* row = &mi[(size_t)dst * 128];
                #pragma unroll
                for (int nt = 0; nt < 2; ++nt)
                    atomicAdd(&row[n0 + nt * 16 + lr], acc2[mt][nt][r] + bias[nt]);
            }
    }
}

// ---- node kernel: stages h from pre-converted hbf when available ----
template <bool USEHBF>
__global__ __launch_bounds__(256, 8)
void node_mfma(const float* __restrict__ h,
               const unsigned short* __restrict__ hbf,
               const float* __restrict__ mi,
               const unsigned short* __restrict__ W1t,
               const float* __restrict__ b1,
               const unsigned short* __restrict__ W2t,
               const float* __restrict__ b2,
               float* __restrict__ out)
{
    __shared__ unsigned short sMem[32 * NK];

    const int tid = threadIdx.x;
    const int g0  = blockIdx.x * 32;

    const float4* h4   = (const float4*)h;
    const short8* hbf8 = (const short8*)hbf;
    const float4* mi4  = (const float4*)mi;
    if (USEHBF) {
        #pragma unroll
        for (int it = 0; it < 2; ++it) {
            const int idx = tid + it * 256;
            const int n  = idx >> 4;
            const int c  = idx & 15;
            const int gn = g0 + n;
            short8 v = (short8){0,0,0,0,0,0,0,0};
            if (gn < N_TOTAL) v = hbf8[(size_t)gn * 16 + c];
            *(short8*)(&sMem[n * NK + c * 8]) = v;
        }
        #pragma unroll
        for (int it = 0; it < 4; ++it) {
            const int idx = tid + it * 256;
            const int n  = idx >> 5;
            const int c  = idx & 31;
            const int gn = g0 + n;
            float4 v = make_float4(0.f, 0.f, 0.f, 0.f);
            if (gn < N_TOTAL) v = mi4[(size_t)gn * 32 + c];
            unsigned short* p = &sMem[n * NK + 128 + c * 4];
            p[0] = f2bf(v.x); p[1] = f2bf(v.y); p[2] = f2bf(v.z); p[3] = f2bf(v.w);
        }
    } else {
        #pragma unroll
        for (int it = 0; it < 8; ++it) {
            const int idx = tid + it * 256;
            const int n  = idx >> 6;
            const int c  = idx & 63;
            const int gn = g0 + n;
            float4 v = make_float4(0.f, 0.f, 0.f, 0.f);
            if (gn < N_TOTAL)
                v = (c < 32) ? h4[(size_t)gn * 32 + c] : mi4[(size_t)gn * 32 + (c - 32)];
            unsigned short* p = &sMem[n * NK + c * 4];
            p[0] = f2bf(v.x); p[1] = f2bf(v.y); p[2] = f2bf(v.z); p[3] = f2bf(v.w);
        }
    }
    __syncthreads();

    const int lane = tid & 63;
    const int w    = tid >> 6;
    const int q    = lane >> 4;
    const int lr   = lane & 15;
    const int n0   = w * 32;

    floatx4 acc[2][2];
    #pragma unroll
    for (int mt = 0; mt < 2; ++mt)
        #pragma unroll
        for (int nt = 0; nt < 2; ++nt)
            acc[mt][nt] = (floatx4){0.f, 0.f, 0.f, 0.f};
    #pragma unroll
    for (int ks = 0; ks < 8; ++ks) {
        const int kb = ks * 32 + q * 8;
        short8 a[2], b[2];
        #pragma unroll
        for (int mt = 0; mt < 2; ++mt)
            a[mt] = *(const short8*)(&sMem[(mt * 16 + lr) * NK + kb]);
        #pragma unroll
        for (int nt = 0; nt < 2; ++nt)
            b[nt] = *(const short8*)(&W1t[(n0 + nt * 16 + lr) * 256 + kb]);
        #pragma unroll
        for (int mt = 0; mt < 2; ++mt)
            #pragma unroll
            for (int nt = 0; nt < 2; ++nt)
                acc[mt][nt] = __builtin_amdgcn_mfma_f32_16x16x32_bf16(
                    a[mt], b[nt], acc[mt][nt], 0, 0, 0);
    }
    __syncthreads();
    {
        float bias[2] = { b1[n0 + lr], b1[n0 + 16 + lr] };
        #pragma unroll
        for (int mt = 0; mt < 2; ++mt)
            #pragma unroll
            for (int nt = 0; nt < 2; ++nt)
                #pragma unroll
                for (int r = 0; r < 4; ++r) {
                    float v = fmaxf(acc[mt][nt][r] + bias[nt], 0.f);
                    sMem[(mt * 16 + q * 4 + r) * HK + n0 + nt * 16 + lr] = f2bf(v);
                }
    }
    __syncthreads();
    floatx4 acc2[2][2];
    #pragma unroll
    for (int mt = 0; mt < 2; ++mt)
        #pragma unroll
        for (int nt = 0; nt < 2; ++nt)
            acc2[mt][nt] = (floatx4){0.f, 0.f, 0.f, 0.f};
    #pragma unroll
    for (int ks = 0; ks < 4; ++ks) {
        const int kb = ks * 32 + q * 8;
        short8 a[2], b[2];
        #pragma unroll
        for (int mt = 0; mt < 2; ++mt)
            a[mt] = *(const short8*)(&sMem[(mt * 16 + lr) * HK + kb]);
        #pragma unroll
        for (int nt = 0; nt < 2; ++nt)
            b[nt] = *(const short8*)(&W2t[(n0 + nt * 16 + lr) * 128 + kb]);
        #pragma unroll
        for (int mt = 0; mt < 2; ++mt)
            #pragma unroll
            for (int nt = 0; nt < 2; ++nt)
                acc2[mt][nt] = __builtin_amdgcn_mfma_f32_16x16x32_bf16(
                    a[mt], b[nt], acc2[mt][nt], 0, 0, 0);
    }
    {
        float bias[2] = { b2[n0 + lr], b2[n0 + 16 + lr] };
        #pragma unroll
        for (int mt = 0; mt < 2; ++mt)
            #pragma unroll
            for (int r = 0; r < 4; ++r) {
                const int gm = g0 + mt * 16 + q * 4 + r;
                if (gm < N_TOTAL) {
                    #pragma unroll
                    for (int nt = 0; nt < 2; ++nt)
                        out[(size_t)gm * 128 + n0 + nt * 16 + lr] =
                            acc2[mt][nt][r] + bias[nt];
                }
            }
    }
}

extern "C" void kernel_launch(void* const* d_in, const int* in_sizes, int n_in,
                              void* d_out, int out_size, void* d_ws, size_t ws_size,
                              hipStream_t stream) {
    const float* h   = (const float*)d_in[0];
    const int*   ei  = (const int*)d_in[1];
    const float* ea  = (const float*)d_in[2];
    const float* We1 = (const float*)d_in[3];
    const float* be1 = (const float*)d_in[4];
    const float* We2 = (const float*)d_in[5];
    const float* be2 = (const float*)d_in[6];
    const float* Wh1 = (const float*)d_in[7];
    const float* bh1 = (const float*)d_in[8];
    const float* Wh2 = (const float*)d_in[9];
    const float* bh2 = (const float*)d_in[10];
    float* out = (float*)d_out;

    const size_t szMi   = (size_t)N_TOTAL * 128 * sizeof(float);
    const size_t szW1t  = 128 * 288 * 2;
    const size_t szW2t  = 128 * 128 * 2;
    const size_t szWh1t = 128 * 256 * 2;
    const size_t szWh2t = 128 * 128 * 2;
    const size_t szHbf  = (size_t)N_TOTAL * 128 * 2;
    const size_t szIds  = (size_t)E_TOTAL * 4;           // srcS / dstS each
    const size_t szEabf = (size_t)E_TOTAL * 32 * 2;      // sorted bf16 edge attrs
    const size_t szHist = (size_t)NBINS * 4;

    const size_t offW1t  = szMi;
    const size_t offW2t  = offW1t + szW1t;
    const size_t offWh1t = offW2t + szW2t;
    const size_t offWh2t = offWh1t + szWh1t;
    const size_t offHbf  = offWh2t + szWh2t;
    const size_t offSrc  = offHbf + szHbf;
    const size_t offDst  = offSrc + szIds;
    const size_t offEabf = offDst + szIds;
    const size_t offHist = offEabf + szEabf;
    const size_t offCur  = offHist + szHist;
    const size_t offP1   = offCur + szHist;
    const size_t offP2   = offP1 + 1024;
    const size_t needFull = offP2 + 1024;
    const size_t needCvt  = offSrc;

    char* wsb = (char*)d_ws;
    float* mi = (float*)wsb;
    unsigned short* W1t  = (unsigned short*)(wsb + offW1t);
    unsigned short* W2t  = (unsigned short*)(wsb + offW2t);
    unsigned short* Wh1t = (unsigned short*)(wsb + offWh1t);
    unsigned short* Wh2t = (unsigned short*)(wsb + offWh2t);
    unsigned short* hbf  = (unsigned short*)(wsb + offHbf);
    int* srcS    = (int*)(wsb + offSrc);
    int* dstS    = (int*)(wsb + offDst);
    unsigned short* eabf = (unsigned short*)(wsb + offEabf);
    int* hist    = (int*)(wsb + offHist);
    int* cursor  = (int*)(wsb + offCur);
    int* partial = (int*)(wsb + offP1);
    int* poff    = (int*)(wsb + offP2);

    const int full   = (ws_size >= needFull) ? 1 : 0;
    const int do_cvt = (ws_size >= needCvt + szHbf) ? 1 : 0;

    prep<<<9971, 256, 0, stream>>>(We1, We2, Wh1, Wh2, W1t, W2t, Wh1t, Wh2t,
                                   h, hbf, do_cvt, full, mi, hist);

    if (full) {
        k_hist<<<E_TOTAL / 256, 256, 0, stream>>>(ei, hist);
        k_scan1<<<NBINS / 256, 256, 0, stream>>>(hist, partial);
        k_scan2<<<1, 256, 0, stream>>>(partial, poff);
        k_scan3<<<NBINS / 256, 256, 0, stream>>>(hist, poff, cursor);
        k_scatter<<<E_TOTAL / 256, 256, 0, stream>>>(ei, ea, cursor, srcS, dstS, eabf);
        edge_mfma_sorted<<<1024, 256, 0, stream>>>(
            hbf, srcS, dstS, eabf, W1t, be1, W2t, be2, mi);
        node_mfma<true><<<(N_TOTAL + 31) / 32, 256, 0, stream>>>(
            h, hbf, mi, Wh1t, bh1, Wh2t, bh2, out);
    } else if (do_cvt) {
        edge_mfma_flat<true><<<E_TOTAL / 32, 256, 0, stream>>>(
            h, hbf, ei, ea, W1t, be1, W2t, be2, mi);
        node_mfma<true><<<(N_TOTAL + 31) / 32, 256, 0, stream>>>(
            h, hbf, mi, Wh1t, bh1, Wh2t, bh2, out);
    } else {
        edge_mfma_flat<false><<<E_TOTAL / 32, 256, 0, stream>>>(
            h, nullptr, ei, ea, W1t, be1, W2t, be2, mi);
        node_mfma<false><<<(N_TOTAL + 31) / 32, 256, 0, stream>>>(
            h, nullptr, mi, Wh1t, bh1, Wh2t, bh2, out);
    }
    (void)in_sizes; (void)n_in; (void)out_size;
}

// Round 6
// 571.890 us; speedup vs baseline: 1.0921x; 1.0798x over previous
//
#include <hip/hip_runtime.h>

#define E_TOTAL 800000
#define N_TOTAL 50000
#define NBINS   50176   // 196*256, padded

typedef __attribute__((ext_vector_type(8))) short short8;
typedef __attribute__((ext_vector_type(4))) float floatx4;

__device__ __forceinline__ unsigned short f2bf(float f) {
    union { float f; unsigned u; } x; x.f = f;
    unsigned r = x.u + 0x7fff + ((x.u >> 16) & 1);   // RNE
    return (unsigned short)(r >> 16);
}

// ---------------- fused prep: weight transpose + mi zero + h->bf16 + hist zero ----------------
__global__ __launch_bounds__(256)
void prep(const float* __restrict__ We1, const float* __restrict__ We2,
          const float* __restrict__ Wh1, const float* __restrict__ Wh2,
          unsigned short* __restrict__ W1t, unsigned short* __restrict__ W2t,
          unsigned short* __restrict__ Wh1t, unsigned short* __restrict__ Wh2t,
          const float* __restrict__ h, unsigned short* __restrict__ hbf,
          int do_cvt, int do_sort,
          float* __restrict__ mi, int* __restrict__ hist)
{
    const int b = blockIdx.x;
    const int tid = threadIdx.x;
    if (b < 400) {
        int t = b * 256 + tid;
        if (t < 36864) {
            W1t[(t & 127) * 288 + (t >> 7)] = f2bf(We1[t]);
        } else if (t < 53248) {
            t -= 36864;
            W2t[(t & 127) * 128 + (t >> 7)] = f2bf(We2[t]);
        } else if (t < 86016) {
            t -= 53248;
            Wh1t[(t & 127) * 256 + (t >> 7)] = f2bf(Wh1[t]);
        } else if (t < 102400) {
            t -= 86016;
            Wh2t[(t & 127) * 128 + (t >> 7)] = f2bf(Wh2[t]);
        }
    } else if (b < 6650) {
        const int t = (b - 400) * 256 + tid;
        ((float4*)mi)[t] = make_float4(0.f, 0.f, 0.f, 0.f);
    } else if (b < 9775) {
        if (do_cvt) {
            const int t = (b - 6650) * 256 + tid;
            const float4* h4 = (const float4*)h;
            float4 a = h4[(size_t)t * 2];
            float4 c = h4[(size_t)t * 2 + 1];
            short8 v = { (short)f2bf(a.x), (short)f2bf(a.y), (short)f2bf(a.z), (short)f2bf(a.w),
                         (short)f2bf(c.x), (short)f2bf(c.y), (short)f2bf(c.z), (short)f2bf(c.w) };
            *(short8*)(&hbf[(size_t)t * 8]) = v;
        }
    } else {
        if (do_sort) hist[(b - 9775) * 256 + tid] = 0;
    }
}

// ---------------- counting sort of edge ids by dst ----------------
__global__ __launch_bounds__(256) void k_hist(const int* __restrict__ ei, int* __restrict__ hist) {
    const int t = blockIdx.x * 256 + threadIdx.x;
    atomicAdd(&hist[ei[E_TOTAL + t]], 1);
}
__global__ __launch_bounds__(256) void k_scan1(const int* __restrict__ hist, int* __restrict__ partial) {
    __shared__ int s[256];
    s[threadIdx.x] = hist[blockIdx.x * 256 + threadIdx.x];
    __syncthreads();
    for (int off = 128; off > 0; off >>= 1) {
        if (threadIdx.x < off) s[threadIdx.x] += s[threadIdx.x + off];
        __syncthreads();
    }
    if (threadIdx.x == 0) partial[blockIdx.x] = s[0];
}
__global__ __launch_bounds__(256)
void k_scan2(const int* __restrict__ partial, int* __restrict__ partialOff) {
    __shared__ int s[256];
    const int t = threadIdx.x;
    const int NP = NBINS / 256;   // 196
    const int v = (t < NP) ? partial[t] : 0;
    s[t] = v; __syncthreads();
    for (int off = 1; off < 256; off <<= 1) {
        int x = (t >= off) ? s[t - off] : 0;
        __syncthreads();
        s[t] += x;
        __syncthreads();
    }
    if (t < NP) partialOff[t] = s[t] - v;   // exclusive prefix
}
__global__ __launch_bounds__(256)
void k_scan3(const int* __restrict__ hist, const int* __restrict__ partialOff,
             int* __restrict__ cursor) {
    __shared__ int s[256];
    const int t = threadIdx.x, g = blockIdx.x * 256 + t;
    const int v = hist[g];
    s[t] = v; __syncthreads();
    for (int off = 1; off < 256; off <<= 1) {
        int x = (t >= off) ? s[t - off] : 0;
        __syncthreads();
        s[t] += x;
        __syncthreads();
    }
    cursor[g] = partialOff[blockIdx.x] + s[t] - v;   // exclusive prefix
}
// scatter: emit sorted src/dst ids AND sorted bf16 edge attrs so the edge
// kernel has zero indirection (no perm, no ei, linear ea reads).
__global__ __launch_bounds__(256)
void k_scatter(const int* __restrict__ ei, const float* __restrict__ ea,
               int* __restrict__ cursor,
               int* __restrict__ srcS, int* __restrict__ dstS,
               unsigned short* __restrict__ eabf) {
    const int t = blockIdx.x * 256 + threadIdx.x;
    const int src = ei[t];
    const int dst = ei[E_TOTAL + t];
    const int pos = atomicAdd(&cursor[dst], 1);
    srcS[pos] = src;
    dstS[pos] = dst;
    const float4* ea4 = (const float4*)ea;
    #pragma unroll
    for (int j = 0; j < 4; ++j) {
        float4 a = ea4[(size_t)t * 8 + j * 2];
        float4 b = ea4[(size_t)t * 8 + j * 2 + 1];
        short8 v = { (short)f2bf(a.x), (short)f2bf(a.y), (short)f2bf(a.z), (short)f2bf(a.w),
                     (short)f2bf(b.x), (short)f2bf(b.y), (short)f2bf(b.z), (short)f2bf(b.w) };
        *(short8*)(&eabf[(size_t)pos * 32 + j * 8]) = v;
    }
}

// ================= MFMA kernels =================
constexpr int XK = 296;  // 288 + 8 pad
constexpr int HK = 136;  // 128 + 8 pad
constexpr int NK = 264;  // 256 + 8 pad
constexpr int FJ = 132;  // fp32 epilogue tile stride

#define MFMA8(A, B, C) { \
    C[0][0] = __builtin_amdgcn_mfma_f32_16x16x32_bf16(A[0], B[0], C[0][0], 0, 0, 0); \
    C[0][1] = __builtin_amdgcn_mfma_f32_16x16x32_bf16(A[0], B[1], C[0][1], 0, 0, 0); \
    C[1][0] = __builtin_amdgcn_mfma_f32_16x16x32_bf16(A[1], B[0], C[1][0], 0, 0, 0); \
    C[1][1] = __builtin_amdgcn_mfma_f32_16x16x32_bf16(A[1], B[1], C[1][1], 0, 0, 0); \
    C[2][0] = __builtin_amdgcn_mfma_f32_16x16x32_bf16(A[2], B[0], C[2][0], 0, 0, 0); \
    C[2][1] = __builtin_amdgcn_mfma_f32_16x16x32_bf16(A[2], B[1], C[2][1], 0, 0, 0); \
    C[3][0] = __builtin_amdgcn_mfma_f32_16x16x32_bf16(A[3], B[0], C[3][0], 0, 0, 0); \
    C[3][1] = __builtin_amdgcn_mfma_f32_16x16x32_bf16(A[3], B[1], C[3][1], 0, 0, 0); }

// ---- persistent pipelined sorted edge kernel (v6 = v5 + register headroom) ----
// v5 post-mortem: gfx950 VGPR/AGPR file is UNIFIED; acc+acc2 (64 AGPR) + 64
// arch VGPR hit the (256,4) 128-reg cap, so the rh[8] staging spilled to
// scratch (+446 MB FETCH / +460 MB WRITE vs v3 = exactly 128B/thread/tile
// round-tripped). (256,3) raises the budget to ~170 so the software pipeline
// actually lives in registers. 3 blocks/CU x 38.4 KB LDS = 115 KB, fits.
__global__ __launch_bounds__(256, 3)
void edge_mfma_sorted(const unsigned short* __restrict__ hbf,
                      const int* __restrict__ srcS,
                      const int* __restrict__ dstS,
                      const unsigned short* __restrict__ eabf,
                      const unsigned short* __restrict__ W1t,  // [128][288]
                      const float* __restrict__ b1,
                      const unsigned short* __restrict__ W2t,  // [128][128]
                      const float* __restrict__ b2,
                      float* __restrict__ mi)
{
    constexpr int NT = E_TOTAL / 64;   // 12500 tiles
    __shared__ alignas(16) unsigned short sMem[64 * XK];  // aliased: sX / sH / sF
    __shared__ int sDstA[64];

    const int tid  = threadIdx.x;
    const short8* hbf8 = (const short8*)hbf;
    const short8* eab8 = (const short8*)eabf;

    const int lane = tid & 63;
    const int w    = tid >> 6;     // 0..3: column group
    const int q    = lane >> 4;
    const int lr   = lane & 15;
    const int n0   = w * 32;
    const int q8   = q * 8;

    // per-tile-invariant addresses
    const int a0 = lr * XK, a1 = (16 + lr) * XK, a2 = (32 + lr) * XK, a3 = (48 + lr) * XK;
    const int h0 = lr * HK, h1 = (16 + lr) * HK, h2 = (32 + lr) * HK, h3 = (48 + lr) * HK;
    const int w1b0 = (n0 + lr) * 288, w1b1 = (n0 + 16 + lr) * 288;
    const int w2b0 = (n0 + lr) * 128, w2b1 = (n0 + 16 + lr) * 128;

    const float bias1[2] = { b1[n0 + lr], b1[n0 + 16 + lr] };
    const float bias2[2] = { b2[n0 + lr], b2[n0 + 16 + lr] };

#define LB1(KS, B) { B[0] = *(const short8*)(&W1t[w1b0 + (KS) * 32 + q8]); \
                     B[1] = *(const short8*)(&W1t[w1b1 + (KS) * 32 + q8]); }
#define LA1(KS, A) { A[0] = *(const short8*)(&sMem[a0 + (KS) * 32 + q8]); \
                     A[1] = *(const short8*)(&sMem[a1 + (KS) * 32 + q8]); \
                     A[2] = *(const short8*)(&sMem[a2 + (KS) * 32 + q8]); \
                     A[3] = *(const short8*)(&sMem[a3 + (KS) * 32 + q8]); }
#define LB2(KS, B) { B[0] = *(const short8*)(&W2t[w2b0 + (KS) * 32 + q8]); \
                     B[1] = *(const short8*)(&W2t[w2b1 + (KS) * 32 + q8]); }
#define LA2(KS, A) { A[0] = *(const short8*)(&sMem[h0 + (KS) * 32 + q8]); \
                     A[1] = *(const short8*)(&sMem[h1 + (KS) * 32 + q8]); \
                     A[2] = *(const short8*)(&sMem[h2 + (KS) * 32 + q8]); \
                     A[3] = *(const short8*)(&sMem[h3 + (KS) * 32 + q8]); }

    // staged next-tile registers
    short8 rh[8];
    short8 rea;
    int    rdst = 0;

    // per-thread invariants for the h staging loop
    const int sc  = tid & 31;        // chunk 0..31
    const int se0 = tid >> 5;        // base edge within tile (stride 8 per item)
    const int scc = sc & 15;         // chunk within node row

    auto LOADR = [&](int tile) {
        const int e0 = tile * 64;
        const int* nodeArr = (sc < 16) ? srcS : dstS;
        #pragma unroll
        for (int k = 0; k < 8; ++k) {
            const int node = nodeArr[e0 + se0 + k * 8];
            rh[k] = hbf8[(size_t)node * 16 + scc];
        }
        rea = eab8[(size_t)tile * 256 + tid];
        if (tid < 64) rdst = dstS[e0 + tid];
    };

    int tile = blockIdx.x;
    LOADR(tile);

    while (tile < NT) {
        // ---- write staged tile -> LDS ----
        {
            const int base = se0 * XK + sc * 8;
            #pragma unroll
            for (int k = 0; k < 8; ++k)
                *(short8*)(&sMem[base + k * 8 * XK]) = rh[k];
            const int e = tid >> 2, c = tid & 3;
            *(short8*)(&sMem[e * XK + 256 + c * 8]) = rea;
            if (tid < 64) sDstA[tid] = rdst;
        }
        __syncthreads();

        // ---- GEMM1: 64x288 @ 288x32, sw-pipelined (b depth-2, a depth-1) ----
        floatx4 acc[4][2];
        #pragma unroll
        for (int mt = 0; mt < 4; ++mt)
            #pragma unroll
            for (int nt = 0; nt < 2; ++nt)
                acc[mt][nt] = (floatx4){0.f, 0.f, 0.f, 0.f};

        {
            short8 aX[4], aY[4], bX[2], bY[2];
            LB1(0, bX); LB1(1, bY); LA1(0, aX);
            LA1(1, aY); MFMA8(aX, bX, acc); LB1(2, bX);   // ks0
            LA1(2, aX); MFMA8(aY, bY, acc); LB1(3, bY);   // ks1
            LA1(3, aY); MFMA8(aX, bX, acc); LB1(4, bX);   // ks2
            LA1(4, aX); MFMA8(aY, bY, acc); LB1(5, bY);   // ks3
            LA1(5, aY); MFMA8(aX, bX, acc); LB1(6, bX);   // ks4
            LA1(6, aX); MFMA8(aY, bY, acc); LB1(7, bY);   // ks5
            LA1(7, aY); MFMA8(aX, bX, acc); LB1(8, bX);   // ks6
            LA1(8, aX); MFMA8(aY, bY, acc);               // ks7
            MFMA8(aX, bX, acc);                           // ks8
        }

        // issue next-tile gather now: rh not live during GEMM1, hides under GEMM2+
        const int nxt = tile + (int)gridDim.x;
        if (nxt < NT) LOADR(nxt);
        __syncthreads();

        {
            #pragma unroll
            for (int mt = 0; mt < 4; ++mt)
                #pragma unroll
                for (int nt = 0; nt < 2; ++nt)
                    #pragma unroll
                    for (int r = 0; r < 4; ++r) {
                        float v = fmaxf(acc[mt][nt][r] + bias1[nt], 0.f);
                        sMem[(mt * 16 + q * 4 + r) * HK + n0 + nt * 16 + lr] = f2bf(v);
                    }
        }
        __syncthreads();

        // ---- GEMM2: 64x128 @ 128x32, sw-pipelined ----
        floatx4 acc2[4][2];
        #pragma unroll
        for (int mt = 0; mt < 4; ++mt)
            #pragma unroll
            for (int nt = 0; nt < 2; ++nt)
                acc2[mt][nt] = (floatx4){0.f, 0.f, 0.f, 0.f};

        {
            short8 aX[4], aY[4], bX[2], bY[2];
            LB2(0, bX); LB2(1, bY); LA2(0, aX);
            LA2(1, aY); MFMA8(aX, bX, acc2); LB2(2, bX);  // ks0
            LA2(2, aX); MFMA8(aY, bY, acc2); LB2(3, bY);  // ks1
            LA2(3, aY); MFMA8(aX, bX, acc2);              // ks2
            MFMA8(aY, bY, acc2);                          // ks3
        }
        __syncthreads();   // GEMM2 LDS reads done before fp32 tile overwrite

        // ---- m_ij tile -> LDS (fp32) ----
        float* sF = (float*)sMem;   // [64][FJ]
        {
            #pragma unroll
            for (int mt = 0; mt < 4; ++mt)
                #pragma unroll
                for (int nt = 0; nt < 2; ++nt)
                    #pragma unroll
                    for (int r = 0; r < 4; ++r)
                        sF[(mt * 16 + q * 4 + r) * FJ + n0 + nt * 16 + lr] =
                            acc2[mt][nt][r] + bias2[nt];
        }
        __syncthreads();

        // ---- run-length-reduced scatter ----
        {
            const int g  = tid >> 7;        // 0..1
            const int j  = tid & 127;
            const int r0 = g * 32;
            float sum = 0.f;
            for (int r = r0; r < r0 + 32; ++r) {
                sum += sF[r * FJ + j];
                const int dst = sDstA[r];
                if (r == r0 + 31 || sDstA[r + 1] != dst) {   // wave-uniform branch
                    atomicAdd(&mi[(size_t)dst * 128 + j], sum);
                    sum = 0.f;
                }
            }
        }
        __syncthreads();   // sF reads done before next tile's LDS write

        tile = nxt;
    }
#undef LB1
#undef LA1
#undef LB2
#undef LA2
}

// ---- flat fallback edge kernel ----
template <bool PRECVT>
__global__ __launch_bounds__(256, 8)
void edge_mfma_flat(const float* __restrict__ h,
                    const unsigned short* __restrict__ hbf,
                    const int* __restrict__ ei,
                    const float* __restrict__ ea,
                    const unsigned short* __restrict__ W1t,
                    const float* __restrict__ b1,
                    const unsigned short* __restrict__ W2t,
                    const float* __restrict__ b2,
                    float* __restrict__ mi)
{
    __shared__ unsigned short sMem[32 * XK];
    __shared__ int sDst[32];

    const int tid = threadIdx.x;
    const int e0  = blockIdx.x * 32;
    if (tid < 32) sDst[tid] = ei[E_TOTAL + e0 + tid];

    const float4* h4   = (const float4*)h;
    const short8* hbf8 = (const short8*)hbf;
    const float4* ea4  = (const float4*)ea;
    #pragma unroll
    for (int it = 0; it < 5; ++it) {
        const int idx = tid + it * 256;
        const int e  = idx / 40;
        const int c  = idx - e * 40;
        const int ge = e0 + e;
        if (c < 32) {
            const int node = (c < 16) ? ei[ge] : ei[E_TOTAL + ge];
            const int cc = c & 15;
            short8 v;
            if (PRECVT) {
                v = hbf8[(size_t)node * 16 + cc];
            } else {
                float4 x = h4[(size_t)node * 32 + cc * 2];
                float4 y = h4[(size_t)node * 32 + cc * 2 + 1];
                v = (short8){ (short)f2bf(x.x), (short)f2bf(x.y), (short)f2bf(x.z), (short)f2bf(x.w),
                              (short)f2bf(y.x), (short)f2bf(y.y), (short)f2bf(y.z), (short)f2bf(y.w) };
            }
            *(short8*)(&sMem[e * XK + c * 8]) = v;
        } else {
            float4 x = ea4[(size_t)ge * 8 + (c - 32)];
            unsigned short* p = &sMem[e * XK + 128 + c * 4];
            p[0] = f2bf(x.x); p[1] = f2bf(x.y); p[2] = f2bf(x.z); p[3] = f2bf(x.w);
        }
    }
    __syncthreads();

    const int lane = tid & 63;
    const int w    = tid >> 6;
    const int q    = lane >> 4;
    const int lr   = lane & 15;
    const int n0   = w * 32;

    floatx4 acc[2][2];
    #pragma unroll
    for (int mt = 0; mt < 2; ++mt)
        #pragma unroll
        for (int nt = 0; nt < 2; ++nt)
            acc[mt][nt] = (floatx4){0.f, 0.f, 0.f, 0.f};
    #pragma unroll
    for (int ks = 0; ks < 9; ++ks) {
        const int kb = ks * 32 + q * 8;
        short8 a[2], b[2];
        #pragma unroll
        for (int mt = 0; mt < 2; ++mt)
            a[mt] = *(const short8*)(&sMem[(mt * 16 + lr) * XK + kb]);
        #pragma unroll
        for (int nt = 0; nt < 2; ++nt)
            b[nt] = *(const short8*)(&W1t[(n0 + nt * 16 + lr) * 288 + kb]);
        #pragma unroll
        for (int mt = 0; mt < 2; ++mt)
            #pragma unroll
            for (int nt = 0; nt < 2; ++nt)
                acc[mt][nt] = __builtin_amdgcn_mfma_f32_16x16x32_bf16(
                    a[mt], b[nt], acc[mt][nt], 0, 0, 0);
    }
    __syncthreads();
    {
        float bias[2] = { b1[n0 + lr], b1[n0 + 16 + lr] };
        #pragma unroll
        for (int mt = 0; mt < 2; ++mt)
            #pragma unroll
            for (int nt = 0; nt < 2; ++nt)
                #pragma unroll
                for (int r = 0; r < 4; ++r) {
                    float v = fmaxf(acc[mt][nt][r] + bias[nt], 0.f);
                    sMem[(mt * 16 + q * 4 + r) * HK + n0 + nt * 16 + lr] = f2bf(v);
                }
    }
    __syncthreads();
    floatx4 acc2[2][2];
    #pragma unroll
    for (int mt = 0; mt < 2; ++mt)
        #pragma unroll
        for (int nt = 0; nt < 2; ++nt)
            acc2[mt][nt] = (floatx4){0.f, 0.f, 0.f, 0.f};
    #pragma unroll
    for (int ks = 0; ks < 4; ++ks) {
        const int kb = ks * 32 + q * 8;
        short8 a[2], b[2];
        #pragma unroll
        for (int mt = 0; mt < 2; ++mt)
            a[mt] = *(const short8*)(&sMem[(mt * 16 + lr) * HK + kb]);
        #pragma unroll
        for (int nt = 0; nt < 2; ++nt)
            b[nt] = *(const short8*)(&W2t[(n0 + nt * 16 + lr) * 128 + kb]);
        #pragma unroll
        for (int mt = 0; mt < 2; ++mt)
            #pragma unroll
            for (int nt = 0; nt < 2; ++nt)
                acc2[mt][nt] = __builtin_amdgcn_mfma_f32_16x16x32_bf16(
                    a[mt], b[nt], acc2[mt][nt], 0, 0, 0);
    }
    {
        float bias[2] = { b2[n0 + lr], b2[n0 + 16 + lr] };
        #pragma unroll
        for (int mt = 0; mt < 2; ++mt)
            #pragma unroll
            for (int r = 0; r < 4; ++r) {
                const int m   = mt * 16 + q * 4 + r;
                const int dst = sDst[m];
                float* row = &mi[(size_t)dst * 128];
                #pragma unroll
                for (int nt = 0; nt < 2; ++nt)
                    atomicAdd(&row[n0 + nt * 16 + lr], acc2[mt][nt][r] + bias[nt]);
            }
    }
}

// ---- node kernel: stages h from pre-converted hbf when available ----
template <bool USEHBF>
__global__ __launch_bounds__(256, 8)
void node_mfma(const float* __restrict__ h,
               const unsigned short* __restrict__ hbf,
               const float* __restrict__ mi,
               const unsigned short* __restrict__ W1t,
               const float* __restrict__ b1,
               const unsigned short* __restrict__ W2t,
               const float* __restrict__ b2,
               float* __restrict__ out)
{
    __shared__ unsigned short sMem[32 * NK];

    const int tid = threadIdx.x;
    const int g0  = blockIdx.x * 32;

    const float4* h4   = (const float4*)h;
    const short8* hbf8 = (const short8*)hbf;
    const float4* mi4  = (const float4*)mi;
    if (USEHBF) {
        #pragma unroll
        for (int it = 0; it < 2; ++it) {
            const int idx = tid + it * 256;
            const int n  = idx >> 4;
            const int c  = idx & 15;
            const int gn = g0 + n;
            short8 v = (short8){0,0,0,0,0,0,0,0};
            if (gn < N_TOTAL) v = hbf8[(size_t)gn * 16 + c];
            *(short8*)(&sMem[n * NK + c * 8]) = v;
        }
        #pragma unroll
        for (int it = 0; it < 4; ++it) {
            const int idx = tid + it * 256;
            const int n  = idx >> 5;
            const int c  = idx & 31;
            const int gn = g0 + n;
            float4 v = make_float4(0.f, 0.f, 0.f, 0.f);
            if (gn < N_TOTAL) v = mi4[(size_t)gn * 32 + c];
            unsigned short* p = &sMem[n * NK + 128 + c * 4];
            p[0] = f2bf(v.x); p[1] = f2bf(v.y); p[2] = f2bf(v.z); p[3] = f2bf(v.w);
        }
    } else {
        #pragma unroll
        for (int it = 0; it < 8; ++it) {
            const int idx = tid + it * 256;
            const int n  = idx >> 6;
            const int c  = idx & 63;
            const int gn = g0 + n;
            float4 v = make_float4(0.f, 0.f, 0.f, 0.f);
            if (gn < N_TOTAL)
                v = (c < 32) ? h4[(size_t)gn * 32 + c] : mi4[(size_t)gn * 32 + (c - 32)];
            unsigned short* p = &sMem[n * NK + c * 4];
            p[0] = f2bf(v.x); p[1] = f2bf(v.y); p[2] = f2bf(v.z); p[3] = f2bf(v.w);
        }
    }
    __syncthreads();

    const int lane = tid & 63;
    const int w    = tid >> 6;
    const int q    = lane >> 4;
    const int lr   = lane & 15;
    const int n0   = w * 32;

    floatx4 acc[2][2];
    #pragma unroll
    for (int mt = 0; mt < 2; ++mt)
        #pragma unroll
        for (int nt = 0; nt < 2; ++nt)
            acc[mt][nt] = (floatx4){0.f, 0.f, 0.f, 0.f};
    #pragma unroll
    for (int ks = 0; ks < 8; ++ks) {
        const int kb = ks * 32 + q * 8;
        short8 a[2], b[2];
        #pragma unroll
        for (int mt = 0; mt < 2; ++mt)
            a[mt] = *(const short8*)(&sMem[(mt * 16 + lr) * NK + kb]);
        #pragma unroll
        for (int nt = 0; nt < 2; ++nt)
            b[nt] = *(const short8*)(&W1t[(n0 + nt * 16 + lr) * 256 + kb]);
        #pragma unroll
        for (int mt = 0; mt < 2; ++mt)
            #pragma unroll
            for (int nt = 0; nt < 2; ++nt)
                acc[mt][nt] = __builtin_amdgcn_mfma_f32_16x16x32_bf16(
                    a[mt], b[nt], acc[mt][nt], 0, 0, 0);
    }
    __syncthreads();
    {
        float bias[2] = { b1[n0 + lr], b1[n0 + 16 + lr] };
        #pragma unroll
        for (int mt = 0; mt < 2; ++mt)
            #pragma unroll
            for (int nt = 0; nt < 2; ++nt)
                #pragma unroll
                for (int r = 0; r < 4; ++r) {
                    float v = fmaxf(acc[mt][nt][r] + bias[nt], 0.f);
                    sMem[(mt * 16 + q * 4 + r) * HK + n0 + nt * 16 + lr] = f2bf(v);
                }
    }
    __syncthreads();
    floatx4 acc2[2][2];
    #pragma unroll
    for (int mt = 0; mt < 2; ++mt)
        #pragma unroll
        for (int nt = 0; nt < 2; ++nt)
            acc2[mt][nt] = (floatx4){0.f, 0.f, 0.f, 0.f};
    #pragma unroll
    for (int ks = 0; ks < 4; ++ks) {
        const int kb = ks * 32 + q * 8;
        short8 a[2], b[2];
        #pragma unroll
        for (int mt = 0; mt < 2; ++mt)
            a[mt] = *(const short8*)(&sMem[(mt * 16 + lr) * HK + kb]);
        #pragma unroll
        for (int nt = 0; nt < 2; ++nt)
            b[nt] = *(const short8*)(&W2t[(n0 + nt * 16 + lr) * 128 + kb]);
        #pragma unroll
        for (int mt = 0; mt < 2; ++mt)
            #pragma unroll
            for (int nt = 0; nt < 2; ++nt)
                acc2[mt][nt] = __builtin_amdgcn_mfma_f32_16x16x32_bf16(
                    a[mt], b[nt], acc2[mt][nt], 0, 0, 0);
    }
    {
        float bias[2] = { b2[n0 + lr], b2[n0 + 16 + lr] };
        #pragma unroll
        for (int mt = 0; mt < 2; ++mt)
            #pragma unroll
            for (int r = 0; r < 4; ++r) {
                const int gm = g0 + mt * 16 + q * 4 + r;
                if (gm < N_TOTAL) {
                    #pragma unroll
                    for (int nt = 0; nt < 2; ++nt)
                        out[(size_t)gm * 128 + n0 + nt * 16 + lr] =
                            acc2[mt][nt][r] + bias[nt];
                }
            }
    }
}

extern "C" void kernel_launch(void* const* d_in, const int* in_sizes, int n_in,
                              void* d_out, int out_size, void* d_ws, size_t ws_size,
                              hipStream_t stream) {
    const float* h   = (const float*)d_in[0];
    const int*   ei  = (const int*)d_in[1];
    const float* ea  = (const float*)d_in[2];
    const float* We1 = (const float*)d_in[3];
    const float* be1 = (const float*)d_in[4];
    const float* We2 = (const float*)d_in[5];
    const float* be2 = (const float*)d_in[6];
    const float* Wh1 = (const float*)d_in[7];
    const float* bh1 = (const float*)d_in[8];
    const float* Wh2 = (const float*)d_in[9];
    const float* bh2 = (const float*)d_in[10];
    float* out = (float*)d_out;

    const size_t szMi   = (size_t)N_TOTAL * 128 * sizeof(float);
    const size_t szW1t  = 128 * 288 * 2;
    const size_t szW2t  = 128 * 128 * 2;
    const size_t szWh1t = 128 * 256 * 2;
    const size_t szWh2t = 128 * 128 * 2;
    const size_t szHbf  = (size_t)N_TOTAL * 128 * 2;
    const size_t szIds  = (size_t)E_TOTAL * 4;           // srcS / dstS each
    const size_t szEabf = (size_t)E_TOTAL * 32 * 2;      // sorted bf16 edge attrs
    const size_t szHist = (size_t)NBINS * 4;

    const size_t offW1t  = szMi;
    const size_t offW2t  = offW1t + szW1t;
    const size_t offWh1t = offW2t + szW2t;
    const size_t offWh2t = offWh1t + szWh1t;
    const size_t offHbf  = offWh2t + szWh2t;
    const size_t offSrc  = offHbf + szHbf;
    const size_t offDst  = offSrc + szIds;
    const size_t offEabf = offDst + szIds;
    const size_t offHist = offEabf + szEabf;
    const size_t offCur  = offHist + szHist;
    const size_t offP1   = offCur + szHist;
    const size_t offP2   = offP1 + 1024;
    const size_t needFull = offP2 + 1024;
    const size_t needCvt  = offSrc;

    char* wsb = (char*)d_ws;
    float* mi = (float*)wsb;
    unsigned short* W1t  = (unsigned short*)(wsb + offW1t);
    unsigned short* W2t  = (unsigned short*)(wsb + offW2t);
    unsigned short* Wh1t = (unsigned short*)(wsb + offWh1t);
    unsigned short* Wh2t = (unsigned short*)(wsb + offWh2t);
    unsigned short* hbf  = (unsigned short*)(wsb + offHbf);
    int* srcS    = (int*)(wsb + offSrc);
    int* dstS    = (int*)(wsb + offDst);
    unsigned short* eabf = (unsigned short*)(wsb + offEabf);
    int* hist    = (int*)(wsb + offHist);
    int* cursor  = (int*)(wsb + offCur);
    int* partial = (int*)(wsb + offP1);
    int* poff    = (int*)(wsb + offP2);

    const int full   = (ws_size >= needFull) ? 1 : 0;
    const int do_cvt = (ws_size >= needCvt + szHbf) ? 1 : 0;

    prep<<<9971, 256, 0, stream>>>(We1, We2, Wh1, Wh2, W1t, W2t, Wh1t, Wh2t,
                                   h, hbf, do_cvt, full, mi, hist);

    if (full) {
        k_hist<<<E_TOTAL / 256, 256, 0, stream>>>(ei, hist);
        k_scan1<<<NBINS / 256, 256, 0, stream>>>(hist, partial);
        k_scan2<<<1, 256, 0, stream>>>(partial, poff);
        k_scan3<<<NBINS / 256, 256, 0, stream>>>(hist, poff, cursor);
        k_scatter<<<E_TOTAL / 256, 256, 0, stream>>>(ei, ea, cursor, srcS, dstS, eabf);
        edge_mfma_sorted<<<768, 256, 0, stream>>>(
            hbf, srcS, dstS, eabf, W1t, be1, W2t, be2, mi);
        node_mfma<true><<<(N_TOTAL + 31) / 32, 256, 0, stream>>>(
            h, hbf, mi, Wh1t, bh1, Wh2t, bh2, out);
    } else if (do_cvt) {
        edge_mfma_flat<true><<<E_TOTAL / 32, 256, 0, stream>>>(
            h, hbf, ei, ea, W1t, be1, W2t, be2, mi);
        node_mfma<true><<<(N_TOTAL + 31) / 32, 256, 0, stream>>>(
            h, hbf, mi, Wh1t, bh1, Wh2t, bh2, out);
    } else {
        edge_mfma_flat<false><<<E_TOTAL / 32, 256, 0, stream>>>(
            h, nullptr, ei, ea, W1t, be1, W2t, be2, mi);
        node_mfma<false><<<(N_TOTAL + 31) / 32, 256, 0, stream>>>(
            h, nullptr, mi, Wh1t, bh1, Wh2t, bh2, out);
    }
    (void)in_sizes; (void)n_in; (void)out_size;
}

// Round 7
// 443.448 us; speedup vs baseline: 1.4084x; 1.2896x over previous
//
#include <hip/hip_runtime.h>

#define E_TOTAL 800000
#define N_TOTAL 50000
#define NBINS   50176   // 196*256, padded

typedef __attribute__((ext_vector_type(8))) short short8;
typedef __attribute__((ext_vector_type(4))) float floatx4;

__device__ __forceinline__ unsigned short f2bf(float f) {
    union { float f; unsigned u; } x; x.f = f;
    unsigned r = x.u + 0x7fff + ((x.u >> 16) & 1);   // RNE
    return (unsigned short)(r >> 16);
}

__device__ __forceinline__ void gload_lds16(const void* g, void* l) {
    __builtin_amdgcn_global_load_lds(
        (const __attribute__((address_space(1))) void*)g,
        (__attribute__((address_space(3))) void*)l, 16, 0, 0);
}
__device__ __forceinline__ void gload_lds4(const void* g, void* l) {
    __builtin_amdgcn_global_load_lds(
        (const __attribute__((address_space(1))) void*)g,
        (__attribute__((address_space(3))) void*)l, 4, 0, 0);
}

// ---------------- fused prep: weight transpose + mi zero + h->bf16 + hist zero ----------------
__global__ __launch_bounds__(256)
void prep(const float* __restrict__ We1, const float* __restrict__ We2,
          const float* __restrict__ Wh1, const float* __restrict__ Wh2,
          unsigned short* __restrict__ W1t, unsigned short* __restrict__ W2t,
          unsigned short* __restrict__ Wh1t, unsigned short* __restrict__ Wh2t,
          const float* __restrict__ h, unsigned short* __restrict__ hbf,
          int do_cvt, int do_sort,
          float* __restrict__ mi, int* __restrict__ hist)
{
    const int b = blockIdx.x;
    const int tid = threadIdx.x;
    if (b < 400) {
        int t = b * 256 + tid;
        if (t < 36864) {
            W1t[(t & 127) * 288 + (t >> 7)] = f2bf(We1[t]);
        } else if (t < 53248) {
            t -= 36864;
            W2t[(t & 127) * 128 + (t >> 7)] = f2bf(We2[t]);
        } else if (t < 86016) {
            t -= 53248;
            Wh1t[(t & 127) * 256 + (t >> 7)] = f2bf(Wh1[t]);
        } else if (t < 102400) {
            t -= 86016;
            Wh2t[(t & 127) * 128 + (t >> 7)] = f2bf(Wh2[t]);
        }
    } else if (b < 6650) {
        const int t = (b - 400) * 256 + tid;
        ((float4*)mi)[t] = make_float4(0.f, 0.f, 0.f, 0.f);
    } else if (b < 9775) {
        if (do_cvt) {
            const int t = (b - 6650) * 256 + tid;
            const float4* h4 = (const float4*)h;
            float4 a = h4[(size_t)t * 2];
            float4 c = h4[(size_t)t * 2 + 1];
            short8 v = { (short)f2bf(a.x), (short)f2bf(a.y), (short)f2bf(a.z), (short)f2bf(a.w),
                         (short)f2bf(c.x), (short)f2bf(c.y), (short)f2bf(c.z), (short)f2bf(c.w) };
            *(short8*)(&hbf[(size_t)t * 8]) = v;
        }
    } else {
        if (do_sort) hist[(b - 9775) * 256 + tid] = 0;
    }
}

// ---------------- counting sort of edge ids by dst ----------------
__global__ __launch_bounds__(256) void k_hist(const int* __restrict__ ei, int* __restrict__ hist) {
    const int t = blockIdx.x * 256 + threadIdx.x;
    atomicAdd(&hist[ei[E_TOTAL + t]], 1);
}
__global__ __launch_bounds__(256) void k_scan1(const int* __restrict__ hist, int* __restrict__ partial) {
    __shared__ int s[256];
    s[threadIdx.x] = hist[blockIdx.x * 256 + threadIdx.x];
    __syncthreads();
    for (int off = 128; off > 0; off >>= 1) {
        if (threadIdx.x < off) s[threadIdx.x] += s[threadIdx.x + off];
        __syncthreads();
    }
    if (threadIdx.x == 0) partial[blockIdx.x] = s[0];
}
__global__ __launch_bounds__(256)
void k_scan2(const int* __restrict__ partial, int* __restrict__ partialOff) {
    __shared__ int s[256];
    const int t = threadIdx.x;
    const int NP = NBINS / 256;   // 196
    const int v = (t < NP) ? partial[t] : 0;
    s[t] = v; __syncthreads();
    for (int off = 1; off < 256; off <<= 1) {
        int x = (t >= off) ? s[t - off] : 0;
        __syncthreads();
        s[t] += x;
        __syncthreads();
    }
    if (t < NP) partialOff[t] = s[t] - v;   // exclusive prefix
}
__global__ __launch_bounds__(256)
void k_scan3(const int* __restrict__ hist, const int* __restrict__ partialOff,
             int* __restrict__ cursor) {
    __shared__ int s[256];
    const int t = threadIdx.x, g = blockIdx.x * 256 + t;
    const int v = hist[g];
    s[t] = v; __syncthreads();
    for (int off = 1; off < 256; off <<= 1) {
        int x = (t >= off) ? s[t - off] : 0;
        __syncthreads();
        s[t] += x;
        __syncthreads();
    }
    cursor[g] = partialOff[blockIdx.x] + s[t] - v;   // exclusive prefix
}
// scatter: emit sorted src/dst ids AND sorted bf16 edge attrs so the edge
// kernel has zero indirection (no perm, no ei, linear ea reads).
__global__ __launch_bounds__(256)
void k_scatter(const int* __restrict__ ei, const float* __restrict__ ea,
               int* __restrict__ cursor,
               int* __restrict__ srcS, int* __restrict__ dstS,
               unsigned short* __restrict__ eabf) {
    const int t = blockIdx.x * 256 + threadIdx.x;
    const int src = ei[t];
    const int dst = ei[E_TOTAL + t];
    const int pos = atomicAdd(&cursor[dst], 1);
    srcS[pos] = src;
    dstS[pos] = dst;
    const float4* ea4 = (const float4*)ea;
    #pragma unroll
    for (int j = 0; j < 4; ++j) {
        float4 a = ea4[(size_t)t * 8 + j * 2];
        float4 b = ea4[(size_t)t * 8 + j * 2 + 1];
        short8 v = { (short)f2bf(a.x), (short)f2bf(a.y), (short)f2bf(a.z), (short)f2bf(a.w),
                     (short)f2bf(b.x), (short)f2bf(b.y), (short)f2bf(b.z), (short)f2bf(b.w) };
        *(short8*)(&eabf[(size_t)pos * 32 + j * 8]) = v;
    }
}

// ================= MFMA kernels =================
constexpr int XK = 296;  // 288 + 8 pad (flat fallback only)
constexpr int HK = 136;  // 128 + 8 pad
constexpr int NK = 264;  // 256 + 8 pad
constexpr int FJ = 132;  // fp32 epilogue tile stride

#define MFMA8(A, B, C) { \
    C[0][0] = __builtin_amdgcn_mfma_f32_16x16x32_bf16(A[0], B[0], C[0][0], 0, 0, 0); \
    C[0][1] = __builtin_amdgcn_mfma_f32_16x16x32_bf16(A[0], B[1], C[0][1], 0, 0, 0); \
    C[1][0] = __builtin_amdgcn_mfma_f32_16x16x32_bf16(A[1], B[0], C[1][0], 0, 0, 0); \
    C[1][1] = __builtin_amdgcn_mfma_f32_16x16x32_bf16(A[1], B[1], C[1][1], 0, 0, 0); \
    C[2][0] = __builtin_amdgcn_mfma_f32_16x16x32_bf16(A[2], B[0], C[2][0], 0, 0, 0); \
    C[2][1] = __builtin_amdgcn_mfma_f32_16x16x32_bf16(A[2], B[1], C[2][1], 0, 0, 0); \
    C[3][0] = __builtin_amdgcn_mfma_f32_16x16x32_bf16(A[3], B[0], C[3][0], 0, 0, 0); \
    C[3][1] = __builtin_amdgcn_mfma_f32_16x16x32_bf16(A[3], B[1], C[3][1], 0, 0, 0); }

// ---- persistent sorted edge kernel (v7: global_load_lds DMA + LDS dbuf) ----
// v6 post-mortem: register staging spilled (~400MB scratch) AND its latency
// was exposed anyway because __syncthreads drains vmcnt(0) at every barrier.
// v7 stages via global_load_lds DMA into a double-buffered LDS X region:
// zero staged registers, DMA issued right after the top barrier so the full
// GEMM1 span hides it. Linear [64][288] rows would 8-way bank-conflict, so
// chunks are XOR-swizzled BOTH sides (pre-swizzled global src + swizzled
// ds_read, rule m173/#21): chunk c stored at p = c ^ (row&15) for c<32.
// H and sF epilogue regions alias the CURRENT X buffer (free after GEMM1).
// LDS = 2*36864 + 1536 = 75264B -> 2 blocks/CU; (256,2) -> 256-reg budget.
__global__ __launch_bounds__(256, 2)
void edge_mfma_sorted(const unsigned short* __restrict__ hbf,
                      const int* __restrict__ srcS,
                      const int* __restrict__ dstS,
                      const unsigned short* __restrict__ eabf,
                      const unsigned short* __restrict__ W1t,  // [128][288]
                      const float* __restrict__ b1,
                      const unsigned short* __restrict__ W2t,  // [128][128]
                      const float* __restrict__ b2,
                      float* __restrict__ mi)
{
    constexpr int NT = E_TOTAL / 64;   // 12500 tiles
    constexpr int XH = 64 * 288;       // shorts per X buffer (36864 B)
    __shared__ alignas(16) unsigned short sMem[2 * XH + 768];
    int* idb = (int*)&sMem[2 * XH];    // 3 x 128 ints: [64 src][64 dst]

    const int tid  = threadIdx.x;
    const int lane = tid & 63;
    const int w    = tid >> 6;     // 0..3: column group
    const int q    = lane >> 4;
    const int lr   = lane & 15;
    const int n0   = w * 32;
    const int q8   = q * 8;
    const int S    = (int)gridDim.x;

    const int w1b0 = (n0 + lr) * 288, w1b1 = (n0 + 16 + lr) * 288;
    const int w2b0 = (n0 + lr) * 128, w2b1 = (n0 + 16 + lr) * 128;
    const int h0 = lr * HK, h1 = (16 + lr) * HK, h2 = (32 + lr) * HK, h3 = (48 + lr) * HK;

    const float bias1[2] = { b1[n0 + lr], b1[n0 + 16 + lr] };
    const float bias2[2] = { b2[n0 + lr], b2[n0 + 16 + lr] };

    // id DMA: wave0 stages 64 src ids, wave1 stages 64 dst ids (linear, 4B)
    auto ID_DMA = [&](int tt, int k) {
        if (w == 0)      gload_lds4(srcS + tt * 64 + lane, &idb[k * 128]);
        else if (w == 1) gload_lds4(dstS + tt * 64 + lane, &idb[k * 128 + 64]);
    };

    // X DMA: stage tile tt into X buffer at short-offset bufS, ids from idb[k].
    // Linear chunk t = j*256+tid covers LDS bytes t*16; row e=t/36, phys p=t%36.
    // Pre-swizzled source: logical chunk c = p^(e&15) for p<32 (involution).
    auto X_DMA = [&](int tt, int bufS, int k) {
        const int* ids = &idb[k * 128];
        #pragma unroll
        for (int j = 0; j < 9; ++j) {
            const int tj = j * 256 + tid;
            const int e  = tj / 36;
            const int p  = tj - e * 36;
            const int c  = (p < 32) ? (p ^ (e & 15)) : p;
            const int node = ids[((c & 16) ? 64 : 0) + e];   // unused when p>=32
            const char* gh = (const char*)hbf + (size_t)node * 256 + (size_t)(c & 15) * 16;
            const char* ge = (const char*)eabf + ((size_t)tt * 64 + e) * 64 + (size_t)(p - 32) * 16;
            const void* g  = (p < 32) ? (const void*)gh : (const void*)ge;
            gload_lds16(g, (void*)&sMem[bufS + j * 2048 + w * 512]);
        }
    };

#define LA1(KS, A) { \
    const int cs = ((KS) < 8) ? ((((KS) * 4 + q) ^ lr) * 8) : ((32 + q) * 8); \
    A[0] = *(const short8*)(&sX[( 0 + lr) * 288 + cs]); \
    A[1] = *(const short8*)(&sX[(16 + lr) * 288 + cs]); \
    A[2] = *(const short8*)(&sX[(32 + lr) * 288 + cs]); \
    A[3] = *(const short8*)(&sX[(48 + lr) * 288 + cs]); }
#define LB1(KS, B) { B[0] = *(const short8*)(&W1t[w1b0 + (KS) * 32 + q8]); \
                     B[1] = *(const short8*)(&W1t[w1b1 + (KS) * 32 + q8]); }
#define LA2(KS, A) { A[0] = *(const short8*)(&sX[h0 + (KS) * 32 + q8]); \
                     A[1] = *(const short8*)(&sX[h1 + (KS) * 32 + q8]); \
                     A[2] = *(const short8*)(&sX[h2 + (KS) * 32 + q8]); \
                     A[3] = *(const short8*)(&sX[h3 + (KS) * 32 + q8]); }
#define LB2(KS, B) { B[0] = *(const short8*)(&W2t[w2b0 + (KS) * 32 + q8]); \
                     B[1] = *(const short8*)(&W2t[w2b1 + (KS) * 32 + q8]); }

    int t  = blockIdx.x;
    int cur = 0, ib = 0;

    // prologue: ids for t and t+S (t+S < NT always: S<=1024 << 12500-512)
    ID_DMA(t, 0);
    ID_DMA(t + S, 1);
    __syncthreads();              // drains id DMA
    X_DMA(t, 0, 0);
    __syncthreads();              // drains X DMA -> X0 ready

    while (t < NT) {
        unsigned short* sX = &sMem[cur * XH];

        // issue next staging first: full GEMM1 span hides the DMA latency
        const int t2 = t + 2 * S;
        if (t2 < NT) ID_DMA(t2, (ib + 2) % 3);
        const int tn = t + S;
        if (tn < NT) X_DMA(tn, (cur ^ 1) * XH, (ib + 1) % 3);

        // ---- GEMM1: 64x288 @ 288x32, sw-pipelined (b depth-2, a depth-1) ----
        floatx4 acc[4][2];
        #pragma unroll
        for (int mt = 0; mt < 4; ++mt)
            #pragma unroll
            for (int nt = 0; nt < 2; ++nt)
                acc[mt][nt] = (floatx4){0.f, 0.f, 0.f, 0.f};
        {
            short8 aX[4], aY[4], bX[2], bY[2];
            LB1(0, bX); LB1(1, bY); LA1(0, aX);
            LA1(1, aY); MFMA8(aX, bX, acc); LB1(2, bX);   // ks0
            LA1(2, aX); MFMA8(aY, bY, acc); LB1(3, bY);   // ks1
            LA1(3, aY); MFMA8(aX, bX, acc); LB1(4, bX);   // ks2
            LA1(4, aX); MFMA8(aY, bY, acc); LB1(5, bY);   // ks3
            LA1(5, aY); MFMA8(aX, bX, acc); LB1(6, bX);   // ks4
            LA1(6, aX); MFMA8(aY, bY, acc); LB1(7, bY);   // ks5
            LA1(7, aY); MFMA8(aX, bX, acc); LB1(8, bX);   // ks6
            LA1(8, aX); MFMA8(aY, bY, acc);               // ks7
            MFMA8(aX, bX, acc);                           // ks8
        }
        __syncthreads();   // X[cur] free; also drains next-tile DMA (done by now)

        // ---- epilogue1 -> H (aliases X[cur]) ----
        {
            #pragma unroll
            for (int mt = 0; mt < 4; ++mt)
                #pragma unroll
                for (int nt = 0; nt < 2; ++nt)
                    #pragma unroll
                    for (int r = 0; r < 4; ++r) {
                        float v = fmaxf(acc[mt][nt][r] + bias1[nt], 0.f);
                        sX[(mt * 16 + q * 4 + r) * HK + n0 + nt * 16 + lr] = f2bf(v);
                    }
        }
        __syncthreads();

        // ---- GEMM2: 64x128 @ 128x32, sw-pipelined ----
        floatx4 acc2[4][2];
        #pragma unroll
        for (int mt = 0; mt < 4; ++mt)
            #pragma unroll
            for (int nt = 0; nt < 2; ++nt)
                acc2[mt][nt] = (floatx4){0.f, 0.f, 0.f, 0.f};
        {
            short8 aX[4], aY[4], bX[2], bY[2];
            LB2(0, bX); LB2(1, bY); LA2(0, aX);
            LA2(1, aY); MFMA8(aX, bX, acc2); LB2(2, bX);  // ks0
            LA2(2, aX); MFMA8(aY, bY, acc2); LB2(3, bY);  // ks1
            LA2(3, aY); MFMA8(aX, bX, acc2);              // ks2
            MFMA8(aY, bY, acc2);                          // ks3
        }
        __syncthreads();   // H free before sF overwrite

        // ---- m_ij tile -> sF (fp32, aliases X[cur]) ----
        float* sF = (float*)sX;   // [64][FJ]
        {
            #pragma unroll
            for (int mt = 0; mt < 4; ++mt)
                #pragma unroll
                for (int nt = 0; nt < 2; ++nt)
                    #pragma unroll
                    for (int r = 0; r < 4; ++r)
                        sF[(mt * 16 + q * 4 + r) * FJ + n0 + nt * 16 + lr] =
                            acc2[mt][nt][r] + bias2[nt];
        }
        __syncthreads();

        // ---- run-length-reduced scatter (dst ids from idb[ib]) ----
        {
            const int* idsDst = &idb[ib * 128 + 64];
            const int g  = tid >> 7;        // 0..1
            const int j  = tid & 127;
            const int r0 = g * 32;
            float sum = 0.f;
            for (int r = r0; r < r0 + 32; ++r) {
                sum += sF[r * FJ + j];
                const int dst = idsDst[r];
                if (r == r0 + 31 || idsDst[r + 1] != dst) {   // wave-uniform branch
                    atomicAdd(&mi[(size_t)dst * 128 + j], sum);
                    sum = 0.f;
                }
            }
        }
        __syncthreads();   // sF/ids reads done before next iteration's writes

        cur ^= 1;
        ib = (ib == 2) ? 0 : ib + 1;
        t = tn;
    }
#undef LA1
#undef LB1
#undef LA2
#undef LB2
}

// ---- flat fallback edge kernel ----
template <bool PRECVT>
__global__ __launch_bounds__(256, 8)
void edge_mfma_flat(const float* __restrict__ h,
                    const unsigned short* __restrict__ hbf,
                    const int* __restrict__ ei,
                    const float* __restrict__ ea,
                    const unsigned short* __restrict__ W1t,
                    const float* __restrict__ b1,
                    const unsigned short* __restrict__ W2t,
                    const float* __restrict__ b2,
                    float* __restrict__ mi)
{
    __shared__ unsigned short sMem[32 * XK];
    __shared__ int sDst[32];

    const int tid = threadIdx.x;
    const int e0  = blockIdx.x * 32;
    if (tid < 32) sDst[tid] = ei[E_TOTAL + e0 + tid];

    const float4* h4   = (const float4*)h;
    const short8* hbf8 = (const short8*)hbf;
    const float4* ea4  = (const float4*)ea;
    #pragma unroll
    for (int it = 0; it < 5; ++it) {
        const int idx = tid + it * 256;
        const int e  = idx / 40;
        const int c  = idx - e * 40;
        const int ge = e0 + e;
        if (c < 32) {
            const int node = (c < 16) ? ei[ge] : ei[E_TOTAL + ge];
            const int cc = c & 15;
            short8 v;
            if (PRECVT) {
                v = hbf8[(size_t)node * 16 + cc];
            } else {
                float4 x = h4[(size_t)node * 32 + cc * 2];
                float4 y = h4[(size_t)node * 32 + cc * 2 + 1];
                v = (short8){ (short)f2bf(x.x), (short)f2bf(x.y), (short)f2bf(x.z), (short)f2bf(x.w),
                              (short)f2bf(y.x), (short)f2bf(y.y), (short)f2bf(y.z), (short)f2bf(y.w) };
            }
            *(short8*)(&sMem[e * XK + c * 8]) = v;
        } else {
            float4 x = ea4[(size_t)ge * 8 + (c - 32)];
            unsigned short* p = &sMem[e * XK + 128 + c * 4];
            p[0] = f2bf(x.x); p[1] = f2bf(x.y); p[2] = f2bf(x.z); p[3] = f2bf(x.w);
        }
    }
    __syncthreads();

    const int lane = tid & 63;
    const int w    = tid >> 6;
    const int q    = lane >> 4;
    const int lr   = lane & 15;
    const int n0   = w * 32;

    floatx4 acc[2][2];
    #pragma unroll
    for (int mt = 0; mt < 2; ++mt)
        #pragma unroll
        for (int nt = 0; nt < 2; ++nt)
            acc[mt][nt] = (floatx4){0.f, 0.f, 0.f, 0.f};
    #pragma unroll
    for (int ks = 0; ks < 9; ++ks) {
        const int kb = ks * 32 + q * 8;
        short8 a[2], b[2];
        #pragma unroll
        for (int mt = 0; mt < 2; ++mt)
            a[mt] = *(const short8*)(&sMem[(mt * 16 + lr) * XK + kb]);
        #pragma unroll
        for (int nt = 0; nt < 2; ++nt)
            b[nt] = *(const short8*)(&W1t[(n0 + nt * 16 + lr) * 288 + kb]);
        #pragma unroll
        for (int mt = 0; mt < 2; ++mt)
            #pragma unroll
            for (int nt = 0; nt < 2; ++nt)
                acc[mt][nt] = __builtin_amdgcn_mfma_f32_16x16x32_bf16(
                    a[mt], b[nt], acc[mt][nt], 0, 0, 0);
    }
    __syncthreads();
    {
        float bias[2] = { b1[n0 + lr], b1[n0 + 16 + lr] };
        #pragma unroll
        for (int mt = 0; mt < 2; ++mt)
            #pragma unroll
            for (int nt = 0; nt < 2; ++nt)
                #pragma unroll
                for (int r = 0; r < 4; ++r) {
                    float v = fmaxf(acc[mt][nt][r] + bias[nt], 0.f);
                    sMem[(mt * 16 + q * 4 + r) * HK + n0 + nt * 16 + lr] = f2bf(v);
                }
    }
    __syncthreads();
    floatx4 acc2[2][2];
    #pragma unroll
    for (int mt = 0; mt < 2; ++mt)
        #pragma unroll
        for (int nt = 0; nt < 2; ++nt)
            acc2[mt][nt] = (floatx4){0.f, 0.f, 0.f, 0.f};
    #pragma unroll
    for (int ks = 0; ks < 4; ++ks) {
        const int kb = ks * 32 + q * 8;
        short8 a[2], b[2];
        #pragma unroll
        for (int mt = 0; mt < 2; ++mt)
            a[mt] = *(const short8*)(&sMem[(mt * 16 + lr) * HK + kb]);
        #pragma unroll
        for (int nt = 0; nt < 2; ++nt)
            b[nt] = *(const short8*)(&W2t[(n0 + nt * 16 + lr) * 128 + kb]);
        #pragma unroll
        for (int mt = 0; mt < 2; ++mt)
            #pragma unroll
            for (int nt = 0; nt < 2; ++nt)
                acc2[mt][nt] = __builtin_amdgcn_mfma_f32_16x16x32_bf16(
                    a[mt], b[nt], acc2[mt][nt], 0, 0, 0);
    }
    {
        float bias[2] = { b2[n0 + lr], b2[n0 + 16 + lr] };
        #pragma unroll
        for (int mt = 0; mt < 2; ++mt)
            #pragma unroll
            for (int r = 0; r < 4; ++r) {
                const int m   = mt * 16 + q * 4 + r;
                const int dst = sDst[m];
                float* row = &mi[(size_t)dst * 128];
                #pragma unroll
                for (int nt = 0; nt < 2; ++nt)
                    atomicAdd(&row[n0 + nt * 16 + lr], acc2[mt][nt][r] + bias[nt]);
            }
    }
}

// ---- node kernel: stages h from pre-converted hbf when available ----
template <bool USEHBF>
__global__ __launch_bounds__(256, 8)
void node_mfma(const float* __restrict__ h,
               const unsigned short* __restrict__ hbf,
               const float* __restrict__ mi,
               const unsigned short* __restrict__ W1t,
               const float* __restrict__ b1,
               const unsigned short* __restrict__ W2t,
               const float* __restrict__ b2,
               float* __restrict__ out)
{
    __shared__ unsigned short sMem[32 * NK];

    const int tid = threadIdx.x;
    const int g0  = blockIdx.x * 32;

    const float4* h4   = (const float4*)h;
    const short8* hbf8 = (const short8*)hbf;
    const float4* mi4  = (const float4*)mi;
    if (USEHBF) {
        #pragma unroll
        for (int it = 0; it < 2; ++it) {
            const int idx = tid + it * 256;
            const int n  = idx >> 4;
            const int c  = idx & 15;
            const int gn = g0 + n;
            short8 v = (short8){0,0,0,0,0,0,0,0};
            if (gn < N_TOTAL) v = hbf8[(size_t)gn * 16 + c];
            *(short8*)(&sMem[n * NK + c * 8]) = v;
        }
        #pragma unroll
        for (int it = 0; it < 4; ++it) {
            const int idx = tid + it * 256;
            const int n  = idx >> 5;
            const int c  = idx & 31;
            const int gn = g0 + n;
            float4 v = make_float4(0.f, 0.f, 0.f, 0.f);
            if (gn < N_TOTAL) v = mi4[(size_t)gn * 32 + c];
            unsigned short* p = &sMem[n * NK + 128 + c * 4];
            p[0] = f2bf(v.x); p[1] = f2bf(v.y); p[2] = f2bf(v.z); p[3] = f2bf(v.w);
        }
    } else {
        #pragma unroll
        for (int it = 0; it < 8; ++it) {
            const int idx = tid + it * 256;
            const int n  = idx >> 6;
            const int c  = idx & 63;
            const int gn = g0 + n;
            float4 v = make_float4(0.f, 0.f, 0.f, 0.f);
            if (gn < N_TOTAL)
                v = (c < 32) ? h4[(size_t)gn * 32 + c] : mi4[(size_t)gn * 32 + (c - 32)];
            unsigned short* p = &sMem[n * NK + c * 4];
            p[0] = f2bf(v.x); p[1] = f2bf(v.y); p[2] = f2bf(v.z); p[3] = f2bf(v.w);
        }
    }
    __syncthreads();

    const int lane = tid & 63;
    const int w    = tid >> 6;
    const int q    = lane >> 4;
    const int lr   = lane & 15;
    const int n0   = w * 32;

    floatx4 acc[2][2];
    #pragma unroll
    for (int mt = 0; mt < 2; ++mt)
        #pragma unroll
        for (int nt = 0; nt < 2; ++nt)
            acc[mt][nt] = (floatx4){0.f, 0.f, 0.f, 0.f};
    #pragma unroll
    for (int ks = 0; ks < 8; ++ks) {
        const int kb = ks * 32 + q * 8;
        short8 a[2], b[2];
        #pragma unroll
        for (int mt = 0; mt < 2; ++mt)
            a[mt] = *(const short8*)(&sMem[(mt * 16 + lr) * NK + kb]);
        #pragma unroll
        for (int nt = 0; nt < 2; ++nt)
            b[nt] = *(const short8*)(&W1t[(n0 + nt * 16 + lr) * 256 + kb]);
        #pragma unroll
        for (int mt = 0; mt < 2; ++mt)
            #pragma unroll
            for (int nt = 0; nt < 2; ++nt)
                acc[mt][nt] = __builtin_amdgcn_mfma_f32_16x16x32_bf16(
                    a[mt], b[nt], acc[mt][nt], 0, 0, 0);
    }
    __syncthreads();
    {
        float bias[2] = { b1[n0 + lr], b1[n0 + 16 + lr] };
        #pragma unroll
        for (int mt = 0; mt < 2; ++mt)
            #pragma unroll
            for (int nt = 0; nt < 2; ++nt)
                #pragma unroll
                for (int r = 0; r < 4; ++r) {
                    float v = fmaxf(acc[mt][nt][r] + bias[nt], 0.f);
                    sMem[(mt * 16 + q * 4 + r) * HK + n0 + nt * 16 + lr] = f2bf(v);
                }
    }
    __syncthreads();
    floatx4 acc2[2][2];
    #pragma unroll
    for (int mt = 0; mt < 2; ++mt)
        #pragma unroll
        for (int nt = 0; nt < 2; ++nt)
            acc2[mt][nt] = (floatx4){0.f, 0.f, 0.f, 0.f};
    #pragma unroll
    for (int ks = 0; ks < 4; ++ks) {
        const int kb = ks * 32 + q * 8;
        short8 a[2], b[2];
        #pragma unroll
        for (int mt = 0; mt < 2; ++mt)
            a[mt] = *(const short8*)(&sMem[(mt * 16 + lr) * HK + kb]);
        #pragma unroll
        for (int nt = 0; nt < 2; ++nt)
            b[nt] = *(const short8*)(&W2t[(n0 + nt * 16 + lr) * 128 + kb]);
        #pragma unroll
        for (int mt = 0; mt < 2; ++mt)
            #pragma unroll
            for (int nt = 0; nt < 2; ++nt)
                acc2[mt][nt] = __builtin_amdgcn_mfma_f32_16x16x32_bf16(
                    a[mt], b[nt], acc2[mt][nt], 0, 0, 0);
    }
    {
        float bias[2] = { b2[n0 + lr], b2[n0 + 16 + lr] };
        #pragma unroll
        for (int mt = 0; mt < 2; ++mt)
            #pragma unroll
            for (int r = 0; r < 4; ++r) {
                const int gm = g0 + mt * 16 + q * 4 + r;
                if (gm < N_TOTAL) {
                    #pragma unroll
                    for (int nt = 0; nt < 2; ++nt)
                        out[(size_t)gm * 128 + n0 + nt * 16 + lr] =
                            acc2[mt][nt][r] + bias[nt];
                }
            }
    }
}

extern "C" void kernel_launch(void* const* d_in, const int* in_sizes, int n_in,
                              void* d_out, int out_size, void* d_ws, size_t ws_size,
                              hipStream_t stream) {
    const float* h   = (const float*)d_in[0];
    const int*   ei  = (const int*)d_in[1];
    const float* ea  = (const float*)d_in[2];
    const float* We1 = (const float*)d_in[3];
    const float* be1 = (const float*)d_in[4];
    const float* We2 = (const float*)d_in[5];
    const float* be2 = (const float*)d_in[6];
    const float* Wh1 = (const float*)d_in[7];
    const float* bh1 = (const float*)d_in[8];
    const float* Wh2 = (const float*)d_in[9];
    const float* bh2 = (const float*)d_in[10];
    float* out = (float*)d_out;

    const size_t szMi   = (size_t)N_TOTAL * 128 * sizeof(float);
    const size_t szW1t  = 128 * 288 * 2;
    const size_t szW2t  = 128 * 128 * 2;
    const size_t szWh1t = 128 * 256 * 2;
    const size_t szWh2t = 128 * 128 * 2;
    const size_t szHbf  = (size_t)N_TOTAL * 128 * 2;
    const size_t szIds  = (size_t)E_TOTAL * 4;           // srcS / dstS each
    const size_t szEabf = (size_t)E_TOTAL * 32 * 2;      // sorted bf16 edge attrs
    const size_t szHist = (size_t)NBINS * 4;

    const size_t offW1t  = szMi;
    const size_t offW2t  = offW1t + szW1t;
    const size_t offWh1t = offW2t + szW2t;
    const size_t offWh2t = offWh1t + szWh1t;
    const size_t offHbf  = offWh2t + szWh2t;
    const size_t offSrc  = offHbf + szHbf;
    const size_t offDst  = offSrc + szIds;
    const size_t offEabf = offDst + szIds;
    const size_t offHist = offEabf + szEabf;
    const size_t offCur  = offHist + szHist;
    const size_t offP1   = offCur + szHist;
    const size_t offP2   = offP1 + 1024;
    const size_t needFull = offP2 + 1024;
    const size_t needCvt  = offSrc;

    char* wsb = (char*)d_ws;
    float* mi = (float*)wsb;
    unsigned short* W1t  = (unsigned short*)(wsb + offW1t);
    unsigned short* W2t  = (unsigned short*)(wsb + offW2t);
    unsigned short* Wh1t = (unsigned short*)(wsb + offWh1t);
    unsigned short* Wh2t = (unsigned short*)(wsb + offWh2t);
    unsigned short* hbf  = (unsigned short*)(wsb + offHbf);
    int* srcS    = (int*)(wsb + offSrc);
    int* dstS    = (int*)(wsb + offDst);
    unsigned short* eabf = (unsigned short*)(wsb + offEabf);
    int* hist    = (int*)(wsb + offHist);
    int* cursor  = (int*)(wsb + offCur);
    int* partial = (int*)(wsb + offP1);
    int* poff    = (int*)(wsb + offP2);

    const int full   = (ws_size >= needFull) ? 1 : 0;
    const int do_cvt = (ws_size >= needCvt + szHbf) ? 1 : 0;

    prep<<<9971, 256, 0, stream>>>(We1, We2, Wh1, Wh2, W1t, W2t, Wh1t, Wh2t,
                                   h, hbf, do_cvt, full, mi, hist);

    if (full) {
        k_hist<<<E_TOTAL / 256, 256, 0, stream>>>(ei, hist);
        k_scan1<<<NBINS / 256, 256, 0, stream>>>(hist, partial);
        k_scan2<<<1, 256, 0, stream>>>(partial, poff);
        k_scan3<<<NBINS / 256, 256, 0, stream>>>(hist, poff, cursor);
        k_scatter<<<E_TOTAL / 256, 256, 0, stream>>>(ei, ea, cursor, srcS, dstS, eabf);
        edge_mfma_sorted<<<512, 256, 0, stream>>>(
            hbf, srcS, dstS, eabf, W1t, be1, W2t, be2, mi);
        node_mfma<true><<<(N_TOTAL + 31) / 32, 256, 0, stream>>>(
            h, hbf, mi, Wh1t, bh1, Wh2t, bh2, out);
    } else if (do_cvt) {
        edge_mfma_flat<true><<<E_TOTAL / 32, 256, 0, stream>>>(
            h, hbf, ei, ea, W1t, be1, W2t, be2, mi);
        node_mfma<true><<<(N_TOTAL + 31) / 32, 256, 0, stream>>>(
            h, hbf, mi, Wh1t, bh1, Wh2t, bh2, out);
    } else {
        edge_mfma_flat<false><<<E_TOTAL / 32, 256, 0, stream>>>(
            h, nullptr, ei, ea, W1t, be1, W2t, be2, mi);
        node_mfma<false><<<(N_TOTAL + 31) / 32, 256, 0, stream>>>(
            h, nullptr, mi, Wh1t, bh1, Wh2t, bh2, out);
    }
    (void)in_sizes; (void)n_in; (void)out_size;
}